// Round 12
// baseline (475.046 us; speedup 1.0000x reference)
//
#include <hip/hip_runtime.h>

#define NB 256   // blocks for hist/scatter passes
#define ND 256   // digit buckets

typedef _Float16 f16x8 __attribute__((ext_vector_type(8)));
typedef _Float16 f16x4 __attribute__((ext_vector_type(4)));
typedef _Float16 f16x2 __attribute__((ext_vector_type(2)));
typedef float f32x4 __attribute__((ext_vector_type(4)));

// ---------------- fp32 -> fp16 row conversion ----------------
__global__ __launch_bounds__(256) void k_cvt(const float* __restrict__ in,
                                             _Float16* __restrict__ out, int n4) {
    int i = blockIdx.x * 256 + threadIdx.x;
    if (i < n4) {
        float4 v = ((const float4*)in)[i];
        ((f16x4*)out)[i] = f16x4{(_Float16)v.x, (_Float16)v.y, (_Float16)v.z, (_Float16)v.w};
    }
}

// ---------------- one-time weight fragment builders ----------------
// 128x64 concat [wl; wr] -> 1024 f16x8 fragments (grid 4 x 256)
__global__ __launch_bounds__(256) void k_wprep128(const float* __restrict__ wl,
                                                  const float* __restrict__ wr,
                                                  f16x8* __restrict__ out) {
    int idx = blockIdx.x * 256 + threadIdx.x;   // 0..1023
    int lane_i = idx & 63, t = idx >> 6;
    int kt = t >> 2, nt = t & 3;
    int col = nt * 16 + (lane_i & 15);
    int krow = kt * 32 + ((lane_i >> 4) << 3);
    f16x8 v;
    #pragma unroll
    for (int j = 0; j < 8; ++j) {
        int k = krow + j;
        const float* W = (k < 64) ? (wl + (size_t)k * 64) : (wr + (size_t)(k - 64) * 64);
        v[j] = (_Float16)W[col];
    }
    out[t * 64 + lane_i] = v;
}

// 64x64 -> 512 f16x8 fragments (grid 2 x 256)
__global__ __launch_bounds__(256) void k_wprep64(const float* __restrict__ wd,
                                                 f16x8* __restrict__ out) {
    int idx = blockIdx.x * 256 + threadIdx.x;   // 0..511
    int lane_i = idx & 63, t = idx >> 6;
    int col = (t & 3) * 16 + (lane_i & 15);
    int krow = (t >> 2) * 32 + ((lane_i >> 4) << 3);
    f16x8 v;
    #pragma unroll
    for (int j = 0; j < 8; ++j)
        v[j] = (_Float16)wd[(size_t)(krow + j) * 64 + col];
    out[t * 64 + lane_i] = v;
}

// ---------------- pass A: per-block digit histograms for BOTH sides ----------------
__global__ __launch_bounds__(256) void k_hist2(const int* __restrict__ src, const int* __restrict__ dst,
                                               int* __restrict__ hist_u, int* __restrict__ hist_m,
                                               int E, int chunk) {
    __shared__ int hu[ND], hm[ND];
    for (int t = threadIdx.x; t < ND; t += 256) { hu[t] = 0; hm[t] = 0; }
    __syncthreads();
    int b = blockIdx.x;
    int e0 = b * chunk, e1 = min(E, e0 + chunk);
    for (int e = e0 + threadIdx.x; e < e1; e += 256) {
        atomicAdd(&hu[src[e] >> 9], 1);
        atomicAdd(&hm[dst[e] >> 7], 1);
    }
    __syncthreads();
    for (int t = threadIdx.x; t < ND; t += 256) {
        hist_u[t * NB + b] = hu[t];
        hist_m[t * NB + b] = hm[t];
    }
}

// ---------------- 2-level inclusive scan -> exclusive offsets ----------------
__global__ void k_scan_local(const int* __restrict__ deg, int* __restrict__ scanned,
                             int* __restrict__ bsums, int N) {
    __shared__ int s[1024];
    int base = blockIdx.x * 1024;
    for (int t = threadIdx.x; t < 1024; t += 256) {
        int i = base + t;
        s[t] = (i < N) ? deg[i] : 0;
    }
    __syncthreads();
    for (int d = 1; d < 1024; d <<= 1) {
        int vals[4];
        for (int j = 0; j < 4; ++j) {
            int t = threadIdx.x + j * 256;
            vals[j] = (t >= d) ? s[t - d] : 0;
        }
        __syncthreads();
        for (int j = 0; j < 4; ++j) {
            int t = threadIdx.x + j * 256;
            s[t] += vals[j];
        }
        __syncthreads();
    }
    for (int t = threadIdx.x; t < 1024; t += 256) {
        int i = base + t;
        if (i < N) scanned[i] = s[t];
    }
    if (threadIdx.x == 0) bsums[blockIdx.x] = s[1023];
}

__global__ void k_scan_carry(int* bsums, int nb) {
    __shared__ int s[256];
    int t = threadIdx.x;
    s[t] = (t < nb) ? bsums[t] : 0;
    __syncthreads();
    for (int d = 1; d < 256; d <<= 1) {
        int v = (t >= d) ? s[t - d] : 0;
        __syncthreads();
        s[t] += v;
        __syncthreads();
    }
    if (t < nb) bsums[t] = s[t];
}

__global__ void k_scan_off(const int* __restrict__ scanned, const int* __restrict__ bsums,
                           int* __restrict__ off, int N) {
    int i = blockIdx.x * 256 + threadIdx.x;
    if (i > N) return;
    int v = 0;
    if (i > 0) {
        int j = i - 1;
        int b = j >> 10;
        v = scanned[j] + (b > 0 ? bsums[b - 1] : 0);
    }
    off[i] = v;
}

// ---------------- pass A scatter: partition edges by top digit (no global atomics) ----------------
__global__ __launch_bounds__(256) void k_scatter(const int* __restrict__ key, const int* __restrict__ val,
                                                 const int* __restrict__ off_flat, int2* __restrict__ tmp,
                                                 int E, int chunk, int shift) {
    __shared__ int cnt[ND];
    for (int t = threadIdx.x; t < ND; t += 256) cnt[t] = 0;
    __syncthreads();
    int b = blockIdx.x;
    int e0 = b * chunk, e1 = min(E, e0 + chunk);
    for (int e = e0 + threadIdx.x; e < e1; e += 256) {
        int k = key[e];
        int d = k >> shift;
        int r = atomicAdd(&cnt[d], 1);           // LDS-only rank
        tmp[off_flat[d * NB + b] + r] = make_int2(k, val[e]);
    }
}

// ---------------- pass B: per-bucket counting sort -> adj + node offsets ----------------
template <int WIDTH>
__global__ __launch_bounds__(256) void k_bucket(const int2* __restrict__ tmp,
                                                const int* __restrict__ off_flat,
                                                int* __restrict__ adj, int* __restrict__ off_node,
                                                int E, int shift, int NN) {
    __shared__ int cnt[WIDTH];
    int d = blockIdx.x;
    int bstart = off_flat[d * NB];
    int bend   = off_flat[(d + 1) * NB];
    for (int t = threadIdx.x; t < WIDTH; t += 256) cnt[t] = 0;
    __syncthreads();
    int bsz = bend - bstart;
    for (int i = threadIdx.x; i < bsz; i += 256)
        atomicAdd(&cnt[tmp[bstart + i].x & (WIDTH - 1)], 1);
    __syncthreads();
    int lane = threadIdx.x;
    if (lane < 64) {
        constexpr int EPL = WIDTH >> 6;
        int vals[EPL];
        int tot = 0;
        #pragma unroll
        for (int j = 0; j < EPL; ++j) { vals[j] = cnt[lane * EPL + j]; tot += vals[j]; }
        int inc = tot;
        #pragma unroll
        for (int o = 1; o < 64; o <<= 1) {
            int tsh = __shfl_up(inc, o, 64);
            if (lane >= o) inc += tsh;
        }
        int ex = inc - tot;
        #pragma unroll
        for (int j = 0; j < EPL; ++j) { cnt[lane * EPL + j] = ex; ex += vals[j]; }
    }
    __syncthreads();
    int base_node = d << shift;
    for (int t = threadIdx.x; t < WIDTH; t += 256) {
        int node = base_node + t;
        if (node < NN) off_node[node] = bstart + cnt[t];
    }
    if (d == 0 && threadIdx.x == 0) off_node[NN] = E;
    __syncthreads();
    for (int i = threadIdx.x; i < bsz; i += 256) {
        int2 e = tmp[bstart + i];
        int r = atomicAdd(&cnt[e.x & (WIDTH - 1)], 1);
        adj[bstart + r] = e.y;
    }
}

// ---------------- movie projection: relu(movie_x @ proj_w + b); fp32 + f16 outputs ----------------
__global__ __launch_bounds__(256, 2) void k_proj(const float* __restrict__ mx,
                                                 const float* __restrict__ w,
                                                 const float* __restrict__ b,
                                                 float* __restrict__ out,
                                                 _Float16* __restrict__ out16, int M) {
    __shared__ float4 wt[64 * 64];      // wt[k4*64+lane] = {w[4k4+j][lane]}, 64 KB
    __shared__ float xs[16][256];       // 16 KB
    for (int t = threadIdx.x; t < 4096; t += 256) {
        int lane_i = t & 63, k4 = t >> 6, kb = k4 * 4;
        wt[t] = make_float4(w[(kb + 0) * 64 + lane_i], w[(kb + 1) * 64 + lane_i],
                            w[(kb + 2) * 64 + lane_i], w[(kb + 3) * 64 + lane_i]);
    }
    __syncthreads();
    int wid = threadIdx.x >> 6, lane = threadIdx.x & 63;
    int r0 = wid * 4;
    float bias = b[lane];
    for (int n0 = blockIdx.x * 16; n0 < M; n0 += gridDim.x * 16) {
        #pragma unroll
        for (int rr = 0; rr < 4; ++rr) {
            int n = n0 + r0 + rr;
            if (n < M)
                ((float4*)&xs[r0 + rr][0])[lane] = ((const float4*)mx)[(size_t)n * 64 + lane];
        }
        float a0 = bias, a1 = bias, a2 = bias, a3 = bias;
        #pragma unroll 2
        for (int k4 = 0; k4 < 64; ++k4) {
            float4 wv = wt[k4 * 64 + lane];
            float4 x0 = *(const float4*)&xs[r0 + 0][k4 * 4];
            float4 x1 = *(const float4*)&xs[r0 + 1][k4 * 4];
            float4 x2 = *(const float4*)&xs[r0 + 2][k4 * 4];
            float4 x3 = *(const float4*)&xs[r0 + 3][k4 * 4];
            #pragma unroll
            for (int j = 0; j < 4; ++j) {
                float wvj = (&wv.x)[j];
                a0 += (&x0.x)[j] * wvj;
                a1 += (&x1.x)[j] * wvj;
                a2 += (&x2.x)[j] * wvj;
                a3 += (&x3.x)[j] * wvj;
            }
        }
        int n = n0 + r0;
        float r[4] = {fmaxf(a0, 0.f), fmaxf(a1, 0.f), fmaxf(a2, 0.f), fmaxf(a3, 0.f)};
        #pragma unroll
        for (int rr = 0; rr < 4; ++rr) {
            if (n + rr < M) {
                out[(size_t)(n + rr) * 64 + lane] = r[rr];
                out16[(size_t)(n + rr) * 64 + lane] = (_Float16)r[rr];
            }
        }
    }
}

// ---------------- gather-side segment mean over f16 rows: one wave per node ----------------
__global__ __launch_bounds__(256) void k_agg_h(const _Float16* __restrict__ x,
                                               const int* __restrict__ adj,
                                               const int* __restrict__ off,
                                               float* __restrict__ out, int N) {
    int node = blockIdx.x * 4 + (threadIdx.x >> 6);
    if (node >= N) return;
    int lane = threadIdx.x & 63;
    int g = lane >> 4, i = lane & 15;
    int s0 = off[node], s1 = off[node + 1];
    float4 a = make_float4(0.f, 0.f, 0.f, 0.f);
    float4 b = make_float4(0.f, 0.f, 0.f, 0.f);
    int e = s0 + g;
    for (; e + 4 < s1; e += 8) {
        f16x4 v = ((const f16x4*)x)[(size_t)adj[e] * 16 + i];
        f16x4 w = ((const f16x4*)x)[(size_t)adj[e + 4] * 16 + i];
        a.x += (float)v[0]; a.y += (float)v[1]; a.z += (float)v[2]; a.w += (float)v[3];
        b.x += (float)w[0]; b.y += (float)w[1]; b.z += (float)w[2]; b.w += (float)w[3];
    }
    if (e < s1) {
        f16x4 v = ((const f16x4*)x)[(size_t)adj[e] * 16 + i];
        a.x += (float)v[0]; a.y += (float)v[1]; a.z += (float)v[2]; a.w += (float)v[3];
    }
    a.x += b.x; a.y += b.y; a.z += b.z; a.w += b.w;
    #pragma unroll
    for (int o = 16; o <= 32; o <<= 1) {
        a.x += __shfl_xor(a.x, o, 64);
        a.y += __shfl_xor(a.y, o, 64);
        a.z += __shfl_xor(a.z, o, 64);
        a.w += __shfl_xor(a.w, o, 64);
    }
    int deg = s1 - s0;
    float scale = (deg > 0) ? 1.0f / (float)deg : 0.f;
    if (g == 0) {
        float4 r = make_float4(a.x * scale, a.y * scale, a.z * scale, a.w * scale);
        ((float4*)out)[(size_t)node * 16 + i] = r;
    }
}

// ---------------- layer-1 transform via MFMA; f16 residual output ----------------
// res16 = f16( self + relu([mean|self] @ [wl;wr] + bl) );  weights pre-fragmented.
__global__ __launch_bounds__(256, 4) void k_trans1_mfma(const float* __restrict__ mean,
                                                        const float* __restrict__ self,
                                                        const f16x8* __restrict__ wfrag,
                                                        const float* __restrict__ bl,
                                                        _Float16* __restrict__ res16, int N) {
    __shared__ f16x8 wf[16 * 64];            // 16 KB
    __shared__ _Float16 xs[64][136];         // 17 KB
    const int tid = threadIdx.x;
    for (int t = tid; t < 1024; t += 256)
        ((float4*)wf)[t] = ((const float4*)wfrag)[t];
    __syncthreads();
    const int w = tid >> 6, lane = tid & 63;
    const int g = lane >> 4, c15 = lane & 15;
    const int w16 = w * 16;
    float blv[4];
    #pragma unroll
    for (int nt = 0; nt < 4; ++nt) blv[nt] = bl[nt * 16 + c15];
    for (int n0 = blockIdx.x * 64; n0 < N; n0 += gridDim.x * 64) {
        for (int idx = lane; idx < 1024; idx += 64) {
            int i = idx >> 6, p = idx & 63;
            int n = n0 + w16 + i;
            float2 v = make_float2(0.f, 0.f);
            if (n < N)
                v = (p < 32) ? *(const float2*)&mean[(size_t)n * 64 + 2 * p]
                             : *(const float2*)&self[(size_t)n * 64 + 2 * (p - 32)];
            *(f16x2*)&xs[w16 + i][2 * p] = f16x2{(_Float16)v.x, (_Float16)v.y};
        }
        f32x4 acc[4];
        #pragma unroll
        for (int nt = 0; nt < 4; ++nt) acc[nt] = f32x4{0.f, 0.f, 0.f, 0.f};
        #pragma unroll
        for (int kt = 0; kt < 4; ++kt) {
            f16x8 af = *(const f16x8*)&xs[w16 + c15][kt * 32 + (g << 3)];
            #pragma unroll
            for (int nt = 0; nt < 4; ++nt)
                acc[nt] = __builtin_amdgcn_mfma_f32_16x16x32_f16(af, wf[(kt * 4 + nt) * 64 + lane],
                                                                 acc[nt], 0, 0, 0);
        }
        #pragma unroll
        for (int nt = 0; nt < 4; ++nt) {
            #pragma unroll
            for (int r = 0; r < 4; ++r) {
                int n = n0 + w16 + g * 4 + r;
                if (n < N) {
                    size_t o = (size_t)n * 64 + nt * 16 + c15;
                    res16[o] = (_Float16)(self[o] + fmaxf(acc[nt][r] + blv[nt], 0.f));
                }
            }
        }
    }
}

// ---------------- layer-2 transform + l2norm + decoder half-projection via MFMA ----------------
// u2 = [mean|res16] @ [wl;wr] + bl ; A = (u2/max(||u2||,1e-12)) @ wd;  weights pre-fragmented.
// NOTE: outA may alias mean (in-place, row-exclusive) -> no __restrict__ on those.
__global__ __launch_bounds__(256, 4) void k_trans2_mfma(const float* mean,
                                                        const _Float16* __restrict__ res16,
                                                        const f16x8* __restrict__ wfrag,
                                                        const f16x8* __restrict__ wdfrag,
                                                        const float* __restrict__ bl,
                                                        float* outA, int N) {
    __shared__ f16x8 wf[16 * 64];            // 16 KB
    __shared__ f16x8 wf2[8 * 64];            // 8 KB
    __shared__ _Float16 xs[64][136];         // 17 KB
    __shared__ _Float16 xs2[64][72];         // 9 KB
    const int tid = threadIdx.x;
    for (int t = tid; t < 1024; t += 256)
        ((float4*)wf)[t] = ((const float4*)wfrag)[t];
    for (int t = tid; t < 512; t += 256)
        ((float4*)wf2)[t] = ((const float4*)wdfrag)[t];
    __syncthreads();
    const int w = tid >> 6, lane = tid & 63;
    const int g = lane >> 4, c15 = lane & 15;
    const int w16 = w * 16;
    float blv[4];
    #pragma unroll
    for (int nt = 0; nt < 4; ++nt) blv[nt] = bl[nt * 16 + c15];
    for (int n0 = blockIdx.x * 64; n0 < N; n0 += gridDim.x * 64) {
        for (int idx = lane; idx < 1024; idx += 64) {
            int i = idx >> 6, p = idx & 63;
            int n = n0 + w16 + i;
            f16x2 h = f16x2{(_Float16)0.f, (_Float16)0.f};
            if (n < N) {
                if (p < 32) {
                    float2 v = *(const float2*)&mean[(size_t)n * 64 + 2 * p];
                    h = f16x2{(_Float16)v.x, (_Float16)v.y};
                } else {
                    h = *(const f16x2*)&res16[(size_t)n * 64 + 2 * (p - 32)];
                }
            }
            *(f16x2*)&xs[w16 + i][2 * p] = h;
        }
        f32x4 acc[4];
        #pragma unroll
        for (int nt = 0; nt < 4; ++nt) acc[nt] = f32x4{0.f, 0.f, 0.f, 0.f};
        #pragma unroll
        for (int kt = 0; kt < 4; ++kt) {
            f16x8 af = *(const f16x8*)&xs[w16 + c15][kt * 32 + (g << 3)];
            #pragma unroll
            for (int nt = 0; nt < 4; ++nt)
                acc[nt] = __builtin_amdgcn_mfma_f32_16x16x32_f16(af, wf[(kt * 4 + nt) * 64 + lane],
                                                                 acc[nt], 0, 0, 0);
        }
        float u2[4][4];
        #pragma unroll
        for (int nt = 0; nt < 4; ++nt)
            #pragma unroll
            for (int r = 0; r < 4; ++r)
                u2[nt][r] = acc[nt][r] + blv[nt];
        float sc[4];
        #pragma unroll
        for (int r = 0; r < 4; ++r) {
            float q = u2[0][r] * u2[0][r] + u2[1][r] * u2[1][r]
                    + u2[2][r] * u2[2][r] + u2[3][r] * u2[3][r];
            q += __shfl_xor(q, 1, 64);
            q += __shfl_xor(q, 2, 64);
            q += __shfl_xor(q, 4, 64);
            q += __shfl_xor(q, 8, 64);
            sc[r] = 1.f / fmaxf(sqrtf(q), 1e-12f);
        }
        #pragma unroll
        for (int nt = 0; nt < 4; ++nt)
            #pragma unroll
            for (int r = 0; r < 4; ++r)
                xs2[w16 + g * 4 + r][nt * 16 + c15] = (_Float16)(u2[nt][r] * sc[r]);
        f32x4 acc2[4];
        #pragma unroll
        for (int nt = 0; nt < 4; ++nt) acc2[nt] = f32x4{0.f, 0.f, 0.f, 0.f};
        #pragma unroll
        for (int kt = 0; kt < 2; ++kt) {
            f16x8 af = *(const f16x8*)&xs2[w16 + c15][kt * 32 + (g << 3)];
            #pragma unroll
            for (int nt = 0; nt < 4; ++nt)
                acc2[nt] = __builtin_amdgcn_mfma_f32_16x16x32_f16(af, wf2[(kt * 4 + nt) * 64 + lane],
                                                                  acc2[nt], 0, 0, 0);
        }
        #pragma unroll
        for (int nt = 0; nt < 4; ++nt) {
            #pragma unroll
            for (int r = 0; r < 4; ++r) {
                int n = n0 + w16 + g * 4 + r;
                if (n < N)
                    outA[(size_t)n * 64 + nt * 16 + c15] = acc2[nt][r];
            }
        }
    }
}

// ---------------- decoder: out = relu(A[ls]+B[ld]+b1) . w2 + b2  (4 edges/wave) ----------------
__global__ __launch_bounds__(256) void k_dec(const float* __restrict__ A,
                                             const float* __restrict__ B,
                                             const int* __restrict__ ls,
                                             const int* __restrict__ ld,
                                             const float* __restrict__ b1,
                                             const float* __restrict__ w2,
                                             const float* __restrict__ b2,
                                             float* __restrict__ out, int EL) {
    int lane = threadIdx.x & 63;
    int g = lane >> 4, i = lane & 15;
    int e = blockIdx.x * 16 + (threadIdx.x >> 6) * 4 + g;
    if (e >= EL) return;
    int u = ls[e], m = ld[e];
    float4 av  = ((const float4*)A)[(size_t)u * 16 + i];
    float4 bv  = ((const float4*)B)[(size_t)m * 16 + i];
    float4 b1v = ((const float4*)b1)[i];
    float4 w2v = ((const float4*)w2)[i];
    float p = fmaxf(av.x + bv.x + b1v.x, 0.f) * w2v.x
            + fmaxf(av.y + bv.y + b1v.y, 0.f) * w2v.y
            + fmaxf(av.z + bv.z + b1v.z, 0.f) * w2v.z
            + fmaxf(av.w + bv.w + b1v.w, 0.f) * w2v.w;
    #pragma unroll
    for (int o = 1; o <= 8; o <<= 1) p += __shfl_xor(p, o, 64);
    if (i == 0) out[e] = p + b2[0];
}

extern "C" void kernel_launch(void* const* d_in, const int* in_sizes, int n_in,
                              void* d_out, int out_size, void* d_ws, size_t ws_size,
                              hipStream_t stream) {
    const float* movie_x  = (const float*)d_in[0];
    const float* user_emb = (const float*)d_in[1];
    const float* proj_w   = (const float*)d_in[2];
    const float* proj_b   = (const float*)d_in[3];
    const float* c1_um_wl = (const float*)d_in[4];
    const float* c1_um_bl = (const float*)d_in[5];
    const float* c1_um_wr = (const float*)d_in[6];
    const float* c1_mu_wl = (const float*)d_in[7];
    const float* c1_mu_bl = (const float*)d_in[8];
    const float* c1_mu_wr = (const float*)d_in[9];
    const float* c2_um_wl = (const float*)d_in[10];
    const float* c2_um_bl = (const float*)d_in[11];
    const float* c2_um_wr = (const float*)d_in[12];
    const float* c2_mu_wl = (const float*)d_in[13];
    const float* c2_mu_bl = (const float*)d_in[14];
    const float* c2_mu_wr = (const float*)d_in[15];
    const float* dec_w1   = (const float*)d_in[16];
    const float* dec_b1   = (const float*)d_in[17];
    const float* dec_w2   = (const float*)d_in[18];
    const float* dec_b2   = (const float*)d_in[19];
    const int* edge_src = (const int*)d_in[20];
    const int* edge_dst = (const int*)d_in[21];
    const int* lbl_src  = (const int*)d_in[22];
    const int* lbl_dst  = (const int*)d_in[23];

    const int M  = in_sizes[0] / 256;
    const int U  = in_sizes[1] / 64;
    const int E  = in_sizes[20];
    const int EL = in_sizes[22];
    float* out = (float*)d_out;

    char* ws = (char*)d_ws;
    size_t off = 0;
    auto alloc = [&](size_t bytes) -> void* {
        off = (off + 255) & ~(size_t)255;
        void* p = ws + off;
        off += bytes;
        return p;
    };
    int* bsums  = (int*)alloc(1024);
    int* off_u  = (int*)alloc((size_t)(U + 1) * 4);
    int* off_m  = (int*)alloc((size_t)(M + 1) * 4);
    int* adj_u  = (int*)alloc((size_t)E * 4);
    int* adj_m  = (int*)alloc((size_t)E * 4);
    f16x8* wtab = (f16x8*)alloc(5120 * 16);                  // 80 KB fragment tables
    float* movie0 = (float*)alloc((size_t)M * 64 * 4);       // fp32, later reused as B
    _Float16* movie16 = (_Float16*)alloc((size_t)M * 64 * 2);
    _Float16* user16  = (_Float16*)alloc((size_t)U * 64 * 2);
    float* mean_m = (float*)alloc((size_t)M * 64 * 4);
    float* mean_u = (float*)alloc((size_t)U * 64 * 4);       // later reused as A (in-place)
    _Float16* m_res16 = (_Float16*)alloc((size_t)M * 64 * 2);
    _Float16* u_res16 = (_Float16*)alloc((size_t)U * 64 * 2);

    f16x8* wf1m = wtab;            // [c1_um_wl; c1_um_wr]
    f16x8* wf1u = wtab + 1024;     // [c1_mu_wl; c1_mu_wr]
    f16x8* wf2m = wtab + 2048;     // [c2_um_wl; c2_um_wr]
    f16x8* wf2u = wtab + 3072;     // [c2_mu_wl; c2_mu_wr]
    f16x8* wdm  = wtab + 4096;     // dec_w1 bottom half (movie B)
    f16x8* wdu  = wtab + 4608;     // dec_w1 top half (user A)

    // CSR-build scratch aliases (all dead before mean_m/mean_u first written):
    int*  hist_u   = (int*)mean_m;            // ND*NB ints = 256 KB
    int*  hist_m   = hist_u + ND * NB;        // 256 KB
    int*  scanned  = hist_m + ND * NB;        // 256 KB
    int*  off_flat = scanned + ND * NB;       // ND*NB+1 ints
    int2* tmp      = (int2*)mean_u;           // E*8 = 16 MB (< 25.6 MB)

    auto cdiv = [](int a, int b) { return (a + b - 1) / b; };
    const int chunk = cdiv(E, NB);
    const int NF = ND * NB;                   // 65536 flat counters

    hipMemsetAsync(hist_u, 0, (size_t)NF * 4, stream);
    hipMemsetAsync(hist_m, 0, (size_t)NF * 4, stream);
    k_hist2<<<NB, 256, 0, stream>>>(edge_src, edge_dst, hist_u, hist_m, E, chunk);

    // one-time weight fragment tables + f16 user table
    k_wprep128<<<4, 256, 0, stream>>>(c1_um_wl, c1_um_wr, wf1m);
    k_wprep128<<<4, 256, 0, stream>>>(c1_mu_wl, c1_mu_wr, wf1u);
    k_wprep128<<<4, 256, 0, stream>>>(c2_um_wl, c2_um_wr, wf2m);
    k_wprep128<<<4, 256, 0, stream>>>(c2_mu_wl, c2_mu_wr, wf2u);
    k_wprep64<<<2, 256, 0, stream>>>(dec_w1 + 64 * 64, wdm);
    k_wprep64<<<2, 256, 0, stream>>>(dec_w1, wdu);
    k_cvt<<<cdiv(U * 16, 256), 256, 0, stream>>>(user_emb, user16, U * 16);

    // movie-side CSR (bucket by dst>>7, width 128)
    k_scan_local<<<NF / 1024, 256, 0, stream>>>(hist_m, scanned, bsums, NF);
    k_scan_carry<<<1, 256, 0, stream>>>(bsums, NF / 1024);
    k_scan_off<<<cdiv(NF + 1, 256), 256, 0, stream>>>(scanned, bsums, off_flat, NF);
    k_scatter<<<NB, 256, 0, stream>>>(edge_dst, edge_src, off_flat, tmp, E, chunk, 7);
    k_bucket<128><<<ND, 256, 0, stream>>>(tmp, off_flat, adj_m, off_m, E, 7, M);

    // user-side CSR (bucket by src>>9, width 512)
    k_scan_local<<<NF / 1024, 256, 0, stream>>>(hist_u, scanned, bsums, NF);
    k_scan_carry<<<1, 256, 0, stream>>>(bsums, NF / 1024);
    k_scan_off<<<cdiv(NF + 1, 256), 256, 0, stream>>>(scanned, bsums, off_flat, NF);
    k_scatter<<<NB, 256, 0, stream>>>(edge_src, edge_dst, off_flat, tmp, E, chunk, 9);
    k_bucket<512><<<ND, 256, 0, stream>>>(tmp, off_flat, adj_u, off_u, E, 9, U);

    k_proj<<<cdiv(M, 16), 256, 0, stream>>>(movie_x, proj_w, proj_b, movie0, movie16, M);

    int gm = min(cdiv(M, 64), 2048);
    int gu = min(cdiv(U, 64), 2048);

    // layer 1 (gathers over f16 tables)
    k_agg_h<<<cdiv(M, 4), 256, 0, stream>>>(user16, adj_m, off_m, mean_m, M);
    k_agg_h<<<cdiv(U, 4), 256, 0, stream>>>(movie16, adj_u, off_u, mean_u, U);
    k_trans1_mfma<<<gm, 256, 0, stream>>>(mean_m, movie0, wf1m, c1_um_bl, m_res16, M);
    k_trans1_mfma<<<gu, 256, 0, stream>>>(mean_u, user_emb, wf1u, c1_mu_bl, u_res16, U);

    // layer 2 (gathers over f16 residuals)
    k_agg_h<<<cdiv(M, 4), 256, 0, stream>>>(u_res16, adj_m, off_m, mean_m, M);
    k_agg_h<<<cdiv(U, 4), 256, 0, stream>>>(m_res16, adj_u, off_u, mean_u, U);
    // B = l2norm(m2) @ W1_bot   (into movie0 buffer)
    k_trans2_mfma<<<gm, 256, 0, stream>>>(mean_m, m_res16, wf2m, wdm, c2_um_bl, movie0, M);
    // A = l2norm(u2) @ W1_top   (in-place into mean_u)
    k_trans2_mfma<<<gu, 256, 0, stream>>>(mean_u, u_res16, wf2u, wdu, c2_mu_bl, mean_u, U);

    // decoder
    k_dec<<<cdiv(EL, 16), 256, 0, stream>>>(mean_u, movie0, lbl_src, lbl_dst,
                                            dec_b1, dec_w2, dec_b2, out, EL);
}

// Round 13
// 470.696 us; speedup vs baseline: 1.0092x; 1.0092x over previous
//
#include <hip/hip_runtime.h>

#define NB 256   // blocks for hist/scatter passes
#define ND 256   // digit buckets

typedef _Float16 f16x8 __attribute__((ext_vector_type(8)));
typedef _Float16 f16x4 __attribute__((ext_vector_type(4)));
typedef _Float16 f16x2 __attribute__((ext_vector_type(2)));
typedef float f32x4 __attribute__((ext_vector_type(4)));

__device__ inline f16x8 cvt8(float4 a, float4 b) {
    return f16x8{(_Float16)a.x, (_Float16)a.y, (_Float16)a.z, (_Float16)a.w,
                 (_Float16)b.x, (_Float16)b.y, (_Float16)b.z, (_Float16)b.w};
}

// ---------------- fp32 -> fp16 row conversion ----------------
__global__ __launch_bounds__(256) void k_cvt(const float* __restrict__ in,
                                             _Float16* __restrict__ out, int n4) {
    int i = blockIdx.x * 256 + threadIdx.x;
    if (i < n4) {
        float4 v = ((const float4*)in)[i];
        ((f16x4*)out)[i] = f16x4{(_Float16)v.x, (_Float16)v.y, (_Float16)v.z, (_Float16)v.w};
    }
}

// ---------------- one-time weight fragment builders ----------------
__global__ __launch_bounds__(256) void k_wprep128(const float* __restrict__ wl,
                                                  const float* __restrict__ wr,
                                                  f16x8* __restrict__ out) {
    int idx = blockIdx.x * 256 + threadIdx.x;   // 0..1023
    int lane_i = idx & 63, t = idx >> 6;
    int kt = t >> 2, nt = t & 3;
    int col = nt * 16 + (lane_i & 15);
    int krow = kt * 32 + ((lane_i >> 4) << 3);
    f16x8 v;
    #pragma unroll
    for (int j = 0; j < 8; ++j) {
        int k = krow + j;
        const float* W = (k < 64) ? (wl + (size_t)k * 64) : (wr + (size_t)(k - 64) * 64);
        v[j] = (_Float16)W[col];
    }
    out[t * 64 + lane_i] = v;
}

__global__ __launch_bounds__(256) void k_wprep64(const float* __restrict__ wd,
                                                 f16x8* __restrict__ out) {
    int idx = blockIdx.x * 256 + threadIdx.x;   // 0..511
    int lane_i = idx & 63, t = idx >> 6;
    int col = (t & 3) * 16 + (lane_i & 15);
    int krow = (t >> 2) * 32 + ((lane_i >> 4) << 3);
    f16x8 v;
    #pragma unroll
    for (int j = 0; j < 8; ++j)
        v[j] = (_Float16)wd[(size_t)(krow + j) * 64 + col];
    out[t * 64 + lane_i] = v;
}

// ---------------- pass A: per-block digit histograms for BOTH sides ----------------
__global__ __launch_bounds__(256) void k_hist2(const int* __restrict__ src, const int* __restrict__ dst,
                                               int* __restrict__ hist_u, int* __restrict__ hist_m,
                                               int E, int chunk) {
    __shared__ int hu[ND], hm[ND];
    for (int t = threadIdx.x; t < ND; t += 256) { hu[t] = 0; hm[t] = 0; }
    __syncthreads();
    int b = blockIdx.x;
    int e0 = b * chunk, e1 = min(E, e0 + chunk);
    for (int e = e0 + threadIdx.x; e < e1; e += 256) {
        atomicAdd(&hu[src[e] >> 9], 1);
        atomicAdd(&hm[dst[e] >> 7], 1);
    }
    __syncthreads();
    for (int t = threadIdx.x; t < ND; t += 256) {
        hist_u[t * NB + b] = hu[t];
        hist_m[t * NB + b] = hm[t];
    }
}

// ---------------- 2-level inclusive scan -> exclusive offsets ----------------
__global__ void k_scan_local(const int* __restrict__ deg, int* __restrict__ scanned,
                             int* __restrict__ bsums, int N) {
    __shared__ int s[1024];
    int base = blockIdx.x * 1024;
    for (int t = threadIdx.x; t < 1024; t += 256) {
        int i = base + t;
        s[t] = (i < N) ? deg[i] : 0;
    }
    __syncthreads();
    for (int d = 1; d < 1024; d <<= 1) {
        int vals[4];
        for (int j = 0; j < 4; ++j) {
            int t = threadIdx.x + j * 256;
            vals[j] = (t >= d) ? s[t - d] : 0;
        }
        __syncthreads();
        for (int j = 0; j < 4; ++j) {
            int t = threadIdx.x + j * 256;
            s[t] += vals[j];
        }
        __syncthreads();
    }
    for (int t = threadIdx.x; t < 1024; t += 256) {
        int i = base + t;
        if (i < N) scanned[i] = s[t];
    }
    if (threadIdx.x == 0) bsums[blockIdx.x] = s[1023];
}

__global__ void k_scan_carry(int* bsums, int nb) {
    __shared__ int s[256];
    int t = threadIdx.x;
    s[t] = (t < nb) ? bsums[t] : 0;
    __syncthreads();
    for (int d = 1; d < 256; d <<= 1) {
        int v = (t >= d) ? s[t - d] : 0;
        __syncthreads();
        s[t] += v;
        __syncthreads();
    }
    if (t < nb) bsums[t] = s[t];
}

__global__ void k_scan_off(const int* __restrict__ scanned, const int* __restrict__ bsums,
                           int* __restrict__ off, int N) {
    int i = blockIdx.x * 256 + threadIdx.x;
    if (i > N) return;
    int v = 0;
    if (i > 0) {
        int j = i - 1;
        int b = j >> 10;
        v = scanned[j] + (b > 0 ? bsums[b - 1] : 0);
    }
    off[i] = v;
}

// ---------------- pass A scatter: partition edges by top digit (no global atomics) ----------------
__global__ __launch_bounds__(256) void k_scatter(const int* __restrict__ key, const int* __restrict__ val,
                                                 const int* __restrict__ off_flat, int2* __restrict__ tmp,
                                                 int E, int chunk, int shift) {
    __shared__ int cnt[ND];
    for (int t = threadIdx.x; t < ND; t += 256) cnt[t] = 0;
    __syncthreads();
    int b = blockIdx.x;
    int e0 = b * chunk, e1 = min(E, e0 + chunk);
    for (int e = e0 + threadIdx.x; e < e1; e += 256) {
        int k = key[e];
        int d = k >> shift;
        int r = atomicAdd(&cnt[d], 1);           // LDS-only rank
        tmp[off_flat[d * NB + b] + r] = make_int2(k, val[e]);
    }
}

// ---------------- pass B: per-bucket counting sort -> adj + node offsets ----------------
template <int WIDTH>
__global__ __launch_bounds__(256) void k_bucket(const int2* __restrict__ tmp,
                                                const int* __restrict__ off_flat,
                                                int* __restrict__ adj, int* __restrict__ off_node,
                                                int E, int shift, int NN) {
    __shared__ int cnt[WIDTH];
    int d = blockIdx.x;
    int bstart = off_flat[d * NB];
    int bend   = off_flat[(d + 1) * NB];
    for (int t = threadIdx.x; t < WIDTH; t += 256) cnt[t] = 0;
    __syncthreads();
    int bsz = bend - bstart;
    for (int i = threadIdx.x; i < bsz; i += 256)
        atomicAdd(&cnt[tmp[bstart + i].x & (WIDTH - 1)], 1);
    __syncthreads();
    int lane = threadIdx.x;
    if (lane < 64) {
        constexpr int EPL = WIDTH >> 6;
        int vals[EPL];
        int tot = 0;
        #pragma unroll
        for (int j = 0; j < EPL; ++j) { vals[j] = cnt[lane * EPL + j]; tot += vals[j]; }
        int inc = tot;
        #pragma unroll
        for (int o = 1; o < 64; o <<= 1) {
            int tsh = __shfl_up(inc, o, 64);
            if (lane >= o) inc += tsh;
        }
        int ex = inc - tot;
        #pragma unroll
        for (int j = 0; j < EPL; ++j) { cnt[lane * EPL + j] = ex; ex += vals[j]; }
    }
    __syncthreads();
    int base_node = d << shift;
    for (int t = threadIdx.x; t < WIDTH; t += 256) {
        int node = base_node + t;
        if (node < NN) off_node[node] = bstart + cnt[t];
    }
    if (d == 0 && threadIdx.x == 0) off_node[NN] = E;
    __syncthreads();
    for (int i = threadIdx.x; i < bsz; i += 256) {
        int2 e = tmp[bstart + i];
        int r = atomicAdd(&cnt[e.x & (WIDTH - 1)], 1);
        adj[bstart + r] = e.y;
    }
}

// ---------------- movie projection: relu(movie_x @ proj_w + b); fp32 + f16 outputs ----------------
__global__ __launch_bounds__(256, 2) void k_proj(const float* __restrict__ mx,
                                                 const float* __restrict__ w,
                                                 const float* __restrict__ b,
                                                 float* __restrict__ out,
                                                 _Float16* __restrict__ out16, int M) {
    __shared__ float4 wt[64 * 64];      // 64 KB
    __shared__ float xs[16][256];       // 16 KB
    for (int t = threadIdx.x; t < 4096; t += 256) {
        int lane_i = t & 63, k4 = t >> 6, kb = k4 * 4;
        wt[t] = make_float4(w[(kb + 0) * 64 + lane_i], w[(kb + 1) * 64 + lane_i],
                            w[(kb + 2) * 64 + lane_i], w[(kb + 3) * 64 + lane_i]);
    }
    __syncthreads();
    int wid = threadIdx.x >> 6, lane = threadIdx.x & 63;
    int r0 = wid * 4;
    float bias = b[lane];
    for (int n0 = blockIdx.x * 16; n0 < M; n0 += gridDim.x * 16) {
        #pragma unroll
        for (int rr = 0; rr < 4; ++rr) {
            int n = n0 + r0 + rr;
            if (n < M)
                ((float4*)&xs[r0 + rr][0])[lane] = ((const float4*)mx)[(size_t)n * 64 + lane];
        }
        float a0 = bias, a1 = bias, a2 = bias, a3 = bias;
        #pragma unroll 2
        for (int k4 = 0; k4 < 64; ++k4) {
            float4 wv = wt[k4 * 64 + lane];
            float4 x0 = *(const float4*)&xs[r0 + 0][k4 * 4];
            float4 x1 = *(const float4*)&xs[r0 + 1][k4 * 4];
            float4 x2 = *(const float4*)&xs[r0 + 2][k4 * 4];
            float4 x3 = *(const float4*)&xs[r0 + 3][k4 * 4];
            #pragma unroll
            for (int j = 0; j < 4; ++j) {
                float wvj = (&wv.x)[j];
                a0 += (&x0.x)[j] * wvj;
                a1 += (&x1.x)[j] * wvj;
                a2 += (&x2.x)[j] * wvj;
                a3 += (&x3.x)[j] * wvj;
            }
        }
        int n = n0 + r0;
        float r[4] = {fmaxf(a0, 0.f), fmaxf(a1, 0.f), fmaxf(a2, 0.f), fmaxf(a3, 0.f)};
        #pragma unroll
        for (int rr = 0; rr < 4; ++rr) {
            if (n + rr < M) {
                out[(size_t)(n + rr) * 64 + lane] = r[rr];
                out16[(size_t)(n + rr) * 64 + lane] = (_Float16)r[rr];
            }
        }
    }
}

// ---------------- gather-side segment mean over f16 rows: one wave per node ----------------
__global__ __launch_bounds__(256) void k_agg_h(const _Float16* __restrict__ x,
                                               const int* __restrict__ adj,
                                               const int* __restrict__ off,
                                               float* __restrict__ out, int N) {
    int node = blockIdx.x * 4 + (threadIdx.x >> 6);
    if (node >= N) return;
    int lane = threadIdx.x & 63;
    int g = lane >> 4, i = lane & 15;
    int s0 = off[node], s1 = off[node + 1];
    float4 a = make_float4(0.f, 0.f, 0.f, 0.f);
    float4 b = make_float4(0.f, 0.f, 0.f, 0.f);
    int e = s0 + g;
    for (; e + 4 < s1; e += 8) {
        f16x4 v = ((const f16x4*)x)[(size_t)adj[e] * 16 + i];
        f16x4 w = ((const f16x4*)x)[(size_t)adj[e + 4] * 16 + i];
        a.x += (float)v[0]; a.y += (float)v[1]; a.z += (float)v[2]; a.w += (float)v[3];
        b.x += (float)w[0]; b.y += (float)w[1]; b.z += (float)w[2]; b.w += (float)w[3];
    }
    if (e < s1) {
        f16x4 v = ((const f16x4*)x)[(size_t)adj[e] * 16 + i];
        a.x += (float)v[0]; a.y += (float)v[1]; a.z += (float)v[2]; a.w += (float)v[3];
    }
    a.x += b.x; a.y += b.y; a.z += b.z; a.w += b.w;
    #pragma unroll
    for (int o = 16; o <= 32; o <<= 1) {
        a.x += __shfl_xor(a.x, o, 64);
        a.y += __shfl_xor(a.y, o, 64);
        a.z += __shfl_xor(a.z, o, 64);
        a.w += __shfl_xor(a.w, o, 64);
    }
    int deg = s1 - s0;
    float scale = (deg > 0) ? 1.0f / (float)deg : 0.f;
    if (g == 0) {
        float4 r = make_float4(a.x * scale, a.y * scale, a.z * scale, a.w * scale);
        ((float4*)out)[(size_t)node * 16 + i] = r;
    }
}

// ---------------- layer-1 transform via MFMA; direct-from-global A-fragments ----------------
// res16 = f16( self + relu([mean|self] @ [wl;wr] + bl) )
// Lane (c15,g): A-row = n0+w16+c15, cols kt*32+g*8..+7 -> contiguous global slice.
__global__ __launch_bounds__(256, 6) void k_trans1_mfma(const float* __restrict__ mean,
                                                        const float* __restrict__ self,
                                                        const f16x8* __restrict__ wfrag,
                                                        const float* __restrict__ bl,
                                                        _Float16* __restrict__ res16, int N) {
    __shared__ f16x8 wf[16 * 64];            // 16 KB
    const int tid = threadIdx.x;
    for (int t = tid; t < 1024; t += 256)
        ((float4*)wf)[t] = ((const float4*)wfrag)[t];
    __syncthreads();
    const int w = tid >> 6, lane = tid & 63;
    const int g = lane >> 4, c15 = lane & 15;
    const int w16 = w * 16;
    float blv[4];
    #pragma unroll
    for (int nt = 0; nt < 4; ++nt) blv[nt] = bl[nt * 16 + c15];
    f16x8 afz;
    #pragma unroll
    for (int j = 0; j < 8; ++j) afz[j] = (_Float16)0.f;
    for (int n0 = blockIdx.x * 64; n0 < N; n0 += gridDim.x * 64) {
        int na = n0 + w16 + c15;                 // A-fragment row for this lane
        f16x8 af[4] = {afz, afz, afz, afz};
        if (na < N) {
            const float* mrow = mean + (size_t)na * 64 + g * 8;
            const float* srow = self + (size_t)na * 64 + g * 8;
            af[0] = cvt8(*(const float4*)mrow, *(const float4*)(mrow + 4));
            af[1] = cvt8(*(const float4*)(mrow + 32), *(const float4*)(mrow + 36));
            af[2] = cvt8(*(const float4*)srow, *(const float4*)(srow + 4));
            af[3] = cvt8(*(const float4*)(srow + 32), *(const float4*)(srow + 36));
        }
        f32x4 acc[4];
        #pragma unroll
        for (int nt = 0; nt < 4; ++nt) acc[nt] = f32x4{0.f, 0.f, 0.f, 0.f};
        #pragma unroll
        for (int kt = 0; kt < 4; ++kt) {
            #pragma unroll
            for (int nt = 0; nt < 4; ++nt)
                acc[nt] = __builtin_amdgcn_mfma_f32_16x16x32_f16(af[kt], wf[(kt * 4 + nt) * 64 + lane],
                                                                 acc[nt], 0, 0, 0);
        }
        #pragma unroll
        for (int nt = 0; nt < 4; ++nt) {
            #pragma unroll
            for (int r = 0; r < 4; ++r) {
                int n = n0 + w16 + g * 4 + r;
                if (n < N) {
                    size_t o = (size_t)n * 64 + nt * 16 + c15;
                    res16[o] = (_Float16)(self[o] + fmaxf(acc[nt][r] + blv[nt], 0.f));
                }
            }
        }
    }
}

// ---------------- layer-2 transform + l2norm + decoder half-projection via MFMA ----------------
// u2 = [mean|res16] @ [wl;wr] + bl ; A = (u2/max(||u2||,1e-12)) @ wd
// Direct-from-global A-fragments; only the u2 transpose goes through LDS.
// NOTE: outA may alias mean (in-place, row-exclusive) -> no __restrict__ on those.
__global__ __launch_bounds__(256, 4) void k_trans2_mfma(const float* mean,
                                                        const _Float16* __restrict__ res16,
                                                        const f16x8* __restrict__ wfrag,
                                                        const f16x8* __restrict__ wdfrag,
                                                        const float* __restrict__ bl,
                                                        float* outA, int N) {
    __shared__ f16x8 wf[16 * 64];            // 16 KB
    __shared__ f16x8 wf2[8 * 64];            // 8 KB
    __shared__ _Float16 xs2[64][72];         // 9 KB (u2 transpose)
    const int tid = threadIdx.x;
    for (int t = tid; t < 1024; t += 256)
        ((float4*)wf)[t] = ((const float4*)wfrag)[t];
    for (int t = tid; t < 512; t += 256)
        ((float4*)wf2)[t] = ((const float4*)wdfrag)[t];
    __syncthreads();
    const int w = tid >> 6, lane = tid & 63;
    const int g = lane >> 4, c15 = lane & 15;
    const int w16 = w * 16;
    float blv[4];
    #pragma unroll
    for (int nt = 0; nt < 4; ++nt) blv[nt] = bl[nt * 16 + c15];
    f16x8 afz;
    #pragma unroll
    for (int j = 0; j < 8; ++j) afz[j] = (_Float16)0.f;
    for (int n0 = blockIdx.x * 64; n0 < N; n0 += gridDim.x * 64) {
        int na = n0 + w16 + c15;
        f16x8 af[4] = {afz, afz, afz, afz};
        if (na < N) {
            const float* mrow = mean + (size_t)na * 64 + g * 8;
            const _Float16* rrow = res16 + (size_t)na * 64 + g * 8;
            af[0] = cvt8(*(const float4*)mrow, *(const float4*)(mrow + 4));
            af[1] = cvt8(*(const float4*)(mrow + 32), *(const float4*)(mrow + 36));
            af[2] = *(const f16x8*)rrow;
            af[3] = *(const f16x8*)(rrow + 32);
        }
        f32x4 acc[4];
        #pragma unroll
        for (int nt = 0; nt < 4; ++nt) acc[nt] = f32x4{0.f, 0.f, 0.f, 0.f};
        #pragma unroll
        for (int kt = 0; kt < 4; ++kt) {
            #pragma unroll
            for (int nt = 0; nt < 4; ++nt)
                acc[nt] = __builtin_amdgcn_mfma_f32_16x16x32_f16(af[kt], wf[(kt * 4 + nt) * 64 + lane],
                                                                 acc[nt], 0, 0, 0);
        }
        float u2[4][4];
        #pragma unroll
        for (int nt = 0; nt < 4; ++nt)
            #pragma unroll
            for (int r = 0; r < 4; ++r)
                u2[nt][r] = acc[nt][r] + blv[nt];
        float sc[4];
        #pragma unroll
        for (int r = 0; r < 4; ++r) {
            float q = u2[0][r] * u2[0][r] + u2[1][r] * u2[1][r]
                    + u2[2][r] * u2[2][r] + u2[3][r] * u2[3][r];
            q += __shfl_xor(q, 1, 64);
            q += __shfl_xor(q, 2, 64);
            q += __shfl_xor(q, 4, 64);
            q += __shfl_xor(q, 8, 64);
            sc[r] = 1.f / fmaxf(sqrtf(q), 1e-12f);
        }
        #pragma unroll
        for (int nt = 0; nt < 4; ++nt)
            #pragma unroll
            for (int r = 0; r < 4; ++r)
                xs2[w16 + g * 4 + r][nt * 16 + c15] = (_Float16)(u2[nt][r] * sc[r]);
        f32x4 acc2[4];
        #pragma unroll
        for (int nt = 0; nt < 4; ++nt) acc2[nt] = f32x4{0.f, 0.f, 0.f, 0.f};
        #pragma unroll
        for (int kt = 0; kt < 2; ++kt) {
            f16x8 af2 = *(const f16x8*)&xs2[w16 + c15][kt * 32 + (g << 3)];
            #pragma unroll
            for (int nt = 0; nt < 4; ++nt)
                acc2[nt] = __builtin_amdgcn_mfma_f32_16x16x32_f16(af2, wf2[(kt * 4 + nt) * 64 + lane],
                                                                  acc2[nt], 0, 0, 0);
        }
        #pragma unroll
        for (int nt = 0; nt < 4; ++nt) {
            #pragma unroll
            for (int r = 0; r < 4; ++r) {
                int n = n0 + w16 + g * 4 + r;
                if (n < N)
                    outA[(size_t)n * 64 + nt * 16 + c15] = acc2[nt][r];
            }
        }
    }
}

// ---------------- decoder: out = relu(A[ls]+B[ld]+b1) . w2 + b2  (4 edges/wave) ----------------
__global__ __launch_bounds__(256) void k_dec(const float* __restrict__ A,
                                             const float* __restrict__ B,
                                             const int* __restrict__ ls,
                                             const int* __restrict__ ld,
                                             const float* __restrict__ b1,
                                             const float* __restrict__ w2,
                                             const float* __restrict__ b2,
                                             float* __restrict__ out, int EL) {
    int lane = threadIdx.x & 63;
    int g = lane >> 4, i = lane & 15;
    int e = blockIdx.x * 16 + (threadIdx.x >> 6) * 4 + g;
    if (e >= EL) return;
    int u = ls[e], m = ld[e];
    float4 av  = ((const float4*)A)[(size_t)u * 16 + i];
    float4 bv  = ((const float4*)B)[(size_t)m * 16 + i];
    float4 b1v = ((const float4*)b1)[i];
    float4 w2v = ((const float4*)w2)[i];
    float p = fmaxf(av.x + bv.x + b1v.x, 0.f) * w2v.x
            + fmaxf(av.y + bv.y + b1v.y, 0.f) * w2v.y
            + fmaxf(av.z + bv.z + b1v.z, 0.f) * w2v.z
            + fmaxf(av.w + bv.w + b1v.w, 0.f) * w2v.w;
    #pragma unroll
    for (int o = 1; o <= 8; o <<= 1) p += __shfl_xor(p, o, 64);
    if (i == 0) out[e] = p + b2[0];
}

extern "C" void kernel_launch(void* const* d_in, const int* in_sizes, int n_in,
                              void* d_out, int out_size, void* d_ws, size_t ws_size,
                              hipStream_t stream) {
    const float* movie_x  = (const float*)d_in[0];
    const float* user_emb = (const float*)d_in[1];
    const float* proj_w   = (const float*)d_in[2];
    const float* proj_b   = (const float*)d_in[3];
    const float* c1_um_wl = (const float*)d_in[4];
    const float* c1_um_bl = (const float*)d_in[5];
    const float* c1_um_wr = (const float*)d_in[6];
    const float* c1_mu_wl = (const float*)d_in[7];
    const float* c1_mu_bl = (const float*)d_in[8];
    const float* c1_mu_wr = (const float*)d_in[9];
    const float* c2_um_wl = (const float*)d_in[10];
    const float* c2_um_bl = (const float*)d_in[11];
    const float* c2_um_wr = (const float*)d_in[12];
    const float* c2_mu_wl = (const float*)d_in[13];
    const float* c2_mu_bl = (const float*)d_in[14];
    const float* c2_mu_wr = (const float*)d_in[15];
    const float* dec_w1   = (const float*)d_in[16];
    const float* dec_b1   = (const float*)d_in[17];
    const float* dec_w2   = (const float*)d_in[18];
    const float* dec_b2   = (const float*)d_in[19];
    const int* edge_src = (const int*)d_in[20];
    const int* edge_dst = (const int*)d_in[21];
    const int* lbl_src  = (const int*)d_in[22];
    const int* lbl_dst  = (const int*)d_in[23];

    const int M  = in_sizes[0] / 256;
    const int U  = in_sizes[1] / 64;
    const int E  = in_sizes[20];
    const int EL = in_sizes[22];
    float* out = (float*)d_out;

    char* ws = (char*)d_ws;
    size_t off = 0;
    auto alloc = [&](size_t bytes) -> void* {
        off = (off + 255) & ~(size_t)255;
        void* p = ws + off;
        off += bytes;
        return p;
    };
    int* bsums  = (int*)alloc(1024);
    int* off_u  = (int*)alloc((size_t)(U + 1) * 4);
    int* off_m  = (int*)alloc((size_t)(M + 1) * 4);
    int* adj_u  = (int*)alloc((size_t)E * 4);
    int* adj_m  = (int*)alloc((size_t)E * 4);
    f16x8* wtab = (f16x8*)alloc(5120 * 16);                  // 80 KB fragment tables
    float* movie0 = (float*)alloc((size_t)M * 64 * 4);       // fp32, later reused as B
    _Float16* movie16 = (_Float16*)alloc((size_t)M * 64 * 2);
    _Float16* user16  = (_Float16*)alloc((size_t)U * 64 * 2);
    float* mean_m = (float*)alloc((size_t)M * 64 * 4);
    float* mean_u = (float*)alloc((size_t)U * 64 * 4);       // later reused as A (in-place)
    _Float16* m_res16 = (_Float16*)alloc((size_t)M * 64 * 2);
    _Float16* u_res16 = (_Float16*)alloc((size_t)U * 64 * 2);

    f16x8* wf1m = wtab;            // [c1_um_wl; c1_um_wr]
    f16x8* wf1u = wtab + 1024;     // [c1_mu_wl; c1_mu_wr]
    f16x8* wf2m = wtab + 2048;     // [c2_um_wl; c2_um_wr]
    f16x8* wf2u = wtab + 3072;     // [c2_mu_wl; c2_mu_wr]
    f16x8* wdm  = wtab + 4096;     // dec_w1 bottom half (movie B)
    f16x8* wdu  = wtab + 4608;     // dec_w1 top half (user A)

    // CSR-build scratch aliases (all dead before mean_m/mean_u first written):
    int*  hist_u   = (int*)mean_m;            // ND*NB ints = 256 KB
    int*  hist_m   = hist_u + ND * NB;        // 256 KB
    int*  scanned  = hist_m + ND * NB;        // 256 KB
    int*  off_flat = scanned + ND * NB;       // ND*NB+1 ints
    int2* tmp      = (int2*)mean_u;           // E*8 = 16 MB (< 25.6 MB)

    auto cdiv = [](int a, int b) { return (a + b - 1) / b; };
    const int chunk = cdiv(E, NB);
    const int NF = ND * NB;                   // 65536 flat counters

    hipMemsetAsync(hist_u, 0, (size_t)NF * 4, stream);
    hipMemsetAsync(hist_m, 0, (size_t)NF * 4, stream);
    k_hist2<<<NB, 256, 0, stream>>>(edge_src, edge_dst, hist_u, hist_m, E, chunk);

    // one-time weight fragment tables + f16 user table
    k_wprep128<<<4, 256, 0, stream>>>(c1_um_wl, c1_um_wr, wf1m);
    k_wprep128<<<4, 256, 0, stream>>>(c1_mu_wl, c1_mu_wr, wf1u);
    k_wprep128<<<4, 256, 0, stream>>>(c2_um_wl, c2_um_wr, wf2m);
    k_wprep128<<<4, 256, 0, stream>>>(c2_mu_wl, c2_mu_wr, wf2u);
    k_wprep64<<<2, 256, 0, stream>>>(dec_w1 + 64 * 64, wdm);
    k_wprep64<<<2, 256, 0, stream>>>(dec_w1, wdu);
    k_cvt<<<cdiv(U * 16, 256), 256, 0, stream>>>(user_emb, user16, U * 16);

    // movie-side CSR (bucket by dst>>7, width 128)
    k_scan_local<<<NF / 1024, 256, 0, stream>>>(hist_m, scanned, bsums, NF);
    k_scan_carry<<<1, 256, 0, stream>>>(bsums, NF / 1024);
    k_scan_off<<<cdiv(NF + 1, 256), 256, 0, stream>>>(scanned, bsums, off_flat, NF);
    k_scatter<<<NB, 256, 0, stream>>>(edge_dst, edge_src, off_flat, tmp, E, chunk, 7);
    k_bucket<128><<<ND, 256, 0, stream>>>(tmp, off_flat, adj_m, off_m, E, 7, M);

    // user-side CSR (bucket by src>>9, width 512)
    k_scan_local<<<NF / 1024, 256, 0, stream>>>(hist_u, scanned, bsums, NF);
    k_scan_carry<<<1, 256, 0, stream>>>(bsums, NF / 1024);
    k_scan_off<<<cdiv(NF + 1, 256), 256, 0, stream>>>(scanned, bsums, off_flat, NF);
    k_scatter<<<NB, 256, 0, stream>>>(edge_src, edge_dst, off_flat, tmp, E, chunk, 9);
    k_bucket<512><<<ND, 256, 0, stream>>>(tmp, off_flat, adj_u, off_u, E, 9, U);

    k_proj<<<cdiv(M, 16), 256, 0, stream>>>(movie_x, proj_w, proj_b, movie0, movie16, M);

    int gm = min(cdiv(M, 64), 2048);
    int gu = min(cdiv(U, 64), 2048);

    // layer 1 (gathers over f16 tables)
    k_agg_h<<<cdiv(M, 4), 256, 0, stream>>>(user16, adj_m, off_m, mean_m, M);
    k_agg_h<<<cdiv(U, 4), 256, 0, stream>>>(movie16, adj_u, off_u, mean_u, U);
    k_trans1_mfma<<<gm, 256, 0, stream>>>(mean_m, movie0, wf1m, c1_um_bl, m_res16, M);
    k_trans1_mfma<<<gu, 256, 0, stream>>>(mean_u, user_emb, wf1u, c1_mu_bl, u_res16, U);

    // layer 2 (gathers over f16 residuals)
    k_agg_h<<<cdiv(M, 4), 256, 0, stream>>>(u_res16, adj_m, off_m, mean_m, M);
    k_agg_h<<<cdiv(U, 4), 256, 0, stream>>>(m_res16, adj_u, off_u, mean_u, U);
    // B = l2norm(m2) @ W1_bot   (into movie0 buffer)
    k_trans2_mfma<<<gm, 256, 0, stream>>>(mean_m, m_res16, wf2m, wdm, c2_um_bl, movie0, M);
    // A = l2norm(u2) @ W1_top   (in-place into mean_u)
    k_trans2_mfma<<<gu, 256, 0, stream>>>(mean_u, u_res16, wf2u, wdu, c2_mu_bl, mean_u, U);

    // decoder
    k_dec<<<cdiv(EL, 16), 256, 0, stream>>>(mean_u, movie0, lbl_src, lbl_dst,
                                            dec_b1, dec_w2, dec_b2, out, EL);
}

// Round 14
// 447.763 us; speedup vs baseline: 1.0609x; 1.0512x over previous
//
#include <hip/hip_runtime.h>

#define NB 256   // blocks for hist/scatter passes
#define ND 256   // digit buckets

typedef _Float16 f16x8 __attribute__((ext_vector_type(8)));
typedef _Float16 f16x4 __attribute__((ext_vector_type(4)));
typedef _Float16 f16x2 __attribute__((ext_vector_type(2)));
typedef float f32x4 __attribute__((ext_vector_type(4)));

__device__ inline f16x8 cvt8(float4 a, float4 b) {
    return f16x8{(_Float16)a.x, (_Float16)a.y, (_Float16)a.z, (_Float16)a.w,
                 (_Float16)b.x, (_Float16)b.y, (_Float16)b.z, (_Float16)b.w};
}

// ---------------- fp32 -> fp16 row conversion ----------------
__global__ __launch_bounds__(256) void k_cvt(const float* __restrict__ in,
                                             _Float16* __restrict__ out, int n4) {
    int i = blockIdx.x * 256 + threadIdx.x;
    if (i < n4) {
        float4 v = ((const float4*)in)[i];
        ((f16x4*)out)[i] = f16x4{(_Float16)v.x, (_Float16)v.y, (_Float16)v.z, (_Float16)v.w};
    }
}

// ---------------- one-time weight fragment builders ----------------
__global__ __launch_bounds__(256) void k_wprep128(const float* __restrict__ wl,
                                                  const float* __restrict__ wr,
                                                  f16x8* __restrict__ out) {
    int idx = blockIdx.x * 256 + threadIdx.x;   // 0..1023
    int lane_i = idx & 63, t = idx >> 6;
    int kt = t >> 2, nt = t & 3;
    int col = nt * 16 + (lane_i & 15);
    int krow = kt * 32 + ((lane_i >> 4) << 3);
    f16x8 v;
    #pragma unroll
    for (int j = 0; j < 8; ++j) {
        int k = krow + j;
        const float* W = (k < 64) ? (wl + (size_t)k * 64) : (wr + (size_t)(k - 64) * 64);
        v[j] = (_Float16)W[col];
    }
    out[t * 64 + lane_i] = v;
}

__global__ __launch_bounds__(256) void k_wprep64(const float* __restrict__ wd,
                                                 f16x8* __restrict__ out) {
    int idx = blockIdx.x * 256 + threadIdx.x;   // 0..511
    int lane_i = idx & 63, t = idx >> 6;
    int col = (t & 3) * 16 + (lane_i & 15);
    int krow = (t >> 2) * 32 + ((lane_i >> 4) << 3);
    f16x8 v;
    #pragma unroll
    for (int j = 0; j < 8; ++j)
        v[j] = (_Float16)wd[(size_t)(krow + j) * 64 + col];
    out[t * 64 + lane_i] = v;
}

// ---------------- pass A: per-block digit histograms for BOTH sides ----------------
__global__ __launch_bounds__(256) void k_hist2(const int* __restrict__ src, const int* __restrict__ dst,
                                               int* __restrict__ hist_u, int* __restrict__ hist_m,
                                               int E, int chunk) {
    __shared__ int hu[ND], hm[ND];
    for (int t = threadIdx.x; t < ND; t += 256) { hu[t] = 0; hm[t] = 0; }
    __syncthreads();
    int b = blockIdx.x;
    int e0 = b * chunk, e1 = min(E, e0 + chunk);
    for (int e = e0 + threadIdx.x; e < e1; e += 256) {
        atomicAdd(&hu[src[e] >> 9], 1);
        atomicAdd(&hm[dst[e] >> 7], 1);
    }
    __syncthreads();
    for (int t = threadIdx.x; t < ND; t += 256) {
        hist_u[t * NB + b] = hu[t];
        hist_m[t * NB + b] = hm[t];
    }
}

// ---------------- 2-level inclusive scan -> exclusive offsets ----------------
__global__ void k_scan_local(const int* __restrict__ deg, int* __restrict__ scanned,
                             int* __restrict__ bsums, int N) {
    __shared__ int s[1024];
    int base = blockIdx.x * 1024;
    for (int t = threadIdx.x; t < 1024; t += 256) {
        int i = base + t;
        s[t] = (i < N) ? deg[i] : 0;
    }
    __syncthreads();
    for (int d = 1; d < 1024; d <<= 1) {
        int vals[4];
        for (int j = 0; j < 4; ++j) {
            int t = threadIdx.x + j * 256;
            vals[j] = (t >= d) ? s[t - d] : 0;
        }
        __syncthreads();
        for (int j = 0; j < 4; ++j) {
            int t = threadIdx.x + j * 256;
            s[t] += vals[j];
        }
        __syncthreads();
    }
    for (int t = threadIdx.x; t < 1024; t += 256) {
        int i = base + t;
        if (i < N) scanned[i] = s[t];
    }
    if (threadIdx.x == 0) bsums[blockIdx.x] = s[1023];
}

__global__ void k_scan_carry(int* bsums, int nb) {
    __shared__ int s[256];
    int t = threadIdx.x;
    s[t] = (t < nb) ? bsums[t] : 0;
    __syncthreads();
    for (int d = 1; d < 256; d <<= 1) {
        int v = (t >= d) ? s[t - d] : 0;
        __syncthreads();
        s[t] += v;
        __syncthreads();
    }
    if (t < nb) bsums[t] = s[t];
}

__global__ void k_scan_off(const int* __restrict__ scanned, const int* __restrict__ bsums,
                           int* __restrict__ off, int N) {
    int i = blockIdx.x * 256 + threadIdx.x;
    if (i > N) return;
    int v = 0;
    if (i > 0) {
        int j = i - 1;
        int b = j >> 10;
        v = scanned[j] + (b > 0 ? bsums[b - 1] : 0);
    }
    off[i] = v;
}

// ---------------- pass A scatter: partition edges by top digit (no global atomics) ----------------
__global__ __launch_bounds__(256) void k_scatter(const int* __restrict__ key, const int* __restrict__ val,
                                                 const int* __restrict__ off_flat, int2* __restrict__ tmp,
                                                 int E, int chunk, int shift) {
    __shared__ int cnt[ND];
    for (int t = threadIdx.x; t < ND; t += 256) cnt[t] = 0;
    __syncthreads();
    int b = blockIdx.x;
    int e0 = b * chunk, e1 = min(E, e0 + chunk);
    for (int e = e0 + threadIdx.x; e < e1; e += 256) {
        int k = key[e];
        int d = k >> shift;
        int r = atomicAdd(&cnt[d], 1);           // LDS-only rank
        tmp[off_flat[d * NB + b] + r] = make_int2(k, val[e]);
    }
}

// ---------------- pass B: per-bucket counting sort -> adj + node offsets ----------------
template <int WIDTH>
__global__ __launch_bounds__(256) void k_bucket(const int2* __restrict__ tmp,
                                                const int* __restrict__ off_flat,
                                                int* __restrict__ adj, int* __restrict__ off_node,
                                                int E, int shift, int NN) {
    __shared__ int cnt[WIDTH];
    int d = blockIdx.x;
    int bstart = off_flat[d * NB];
    int bend   = off_flat[(d + 1) * NB];
    for (int t = threadIdx.x; t < WIDTH; t += 256) cnt[t] = 0;
    __syncthreads();
    int bsz = bend - bstart;
    for (int i = threadIdx.x; i < bsz; i += 256)
        atomicAdd(&cnt[tmp[bstart + i].x & (WIDTH - 1)], 1);
    __syncthreads();
    int lane = threadIdx.x;
    if (lane < 64) {
        constexpr int EPL = WIDTH >> 6;
        int vals[EPL];
        int tot = 0;
        #pragma unroll
        for (int j = 0; j < EPL; ++j) { vals[j] = cnt[lane * EPL + j]; tot += vals[j]; }
        int inc = tot;
        #pragma unroll
        for (int o = 1; o < 64; o <<= 1) {
            int tsh = __shfl_up(inc, o, 64);
            if (lane >= o) inc += tsh;
        }
        int ex = inc - tot;
        #pragma unroll
        for (int j = 0; j < EPL; ++j) { cnt[lane * EPL + j] = ex; ex += vals[j]; }
    }
    __syncthreads();
    int base_node = d << shift;
    for (int t = threadIdx.x; t < WIDTH; t += 256) {
        int node = base_node + t;
        if (node < NN) off_node[node] = bstart + cnt[t];
    }
    if (d == 0 && threadIdx.x == 0) off_node[NN] = E;
    __syncthreads();
    for (int i = threadIdx.x; i < bsz; i += 256) {
        int2 e = tmp[bstart + i];
        int r = atomicAdd(&cnt[e.x & (WIDTH - 1)], 1);
        adj[bstart + r] = e.y;
    }
}

// ---------------- movie projection: relu(movie_x @ proj_w + b); fp32 + f16 outputs ----------------
__global__ __launch_bounds__(256, 2) void k_proj(const float* __restrict__ mx,
                                                 const float* __restrict__ w,
                                                 const float* __restrict__ b,
                                                 float* __restrict__ out,
                                                 _Float16* __restrict__ out16, int M) {
    __shared__ float4 wt[64 * 64];      // 64 KB
    __shared__ float xs[16][256];       // 16 KB
    for (int t = threadIdx.x; t < 4096; t += 256) {
        int lane_i = t & 63, k4 = t >> 6, kb = k4 * 4;
        wt[t] = make_float4(w[(kb + 0) * 64 + lane_i], w[(kb + 1) * 64 + lane_i],
                            w[(kb + 2) * 64 + lane_i], w[(kb + 3) * 64 + lane_i]);
    }
    __syncthreads();
    int wid = threadIdx.x >> 6, lane = threadIdx.x & 63;
    int r0 = wid * 4;
    float bias = b[lane];
    for (int n0 = blockIdx.x * 16; n0 < M; n0 += gridDim.x * 16) {
        #pragma unroll
        for (int rr = 0; rr < 4; ++rr) {
            int n = n0 + r0 + rr;
            if (n < M)
                ((float4*)&xs[r0 + rr][0])[lane] = ((const float4*)mx)[(size_t)n * 64 + lane];
        }
        float a0 = bias, a1 = bias, a2 = bias, a3 = bias;
        #pragma unroll 2
        for (int k4 = 0; k4 < 64; ++k4) {
            float4 wv = wt[k4 * 64 + lane];
            float4 x0 = *(const float4*)&xs[r0 + 0][k4 * 4];
            float4 x1 = *(const float4*)&xs[r0 + 1][k4 * 4];
            float4 x2 = *(const float4*)&xs[r0 + 2][k4 * 4];
            float4 x3 = *(const float4*)&xs[r0 + 3][k4 * 4];
            #pragma unroll
            for (int j = 0; j < 4; ++j) {
                float wvj = (&wv.x)[j];
                a0 += (&x0.x)[j] * wvj;
                a1 += (&x1.x)[j] * wvj;
                a2 += (&x2.x)[j] * wvj;
                a3 += (&x3.x)[j] * wvj;
            }
        }
        int n = n0 + r0;
        float r[4] = {fmaxf(a0, 0.f), fmaxf(a1, 0.f), fmaxf(a2, 0.f), fmaxf(a3, 0.f)};
        #pragma unroll
        for (int rr = 0; rr < 4; ++rr) {
            if (n + rr < M) {
                out[(size_t)(n + rr) * 64 + lane] = r[rr];
                out16[(size_t)(n + rr) * 64 + lane] = (_Float16)r[rr];
            }
        }
    }
}

// ---------------- gather-side segment mean, packed-f16 accumulate; f16 mean output ----------------
// 8 lanes per row (f16x8 = 16B each); accumulate in f16 via v_pk_add_f16.
__global__ __launch_bounds__(256) void k_agg_h(const _Float16* __restrict__ x,
                                               const int* __restrict__ adj,
                                               const int* __restrict__ off,
                                               _Float16* __restrict__ out16, int N) {
    int node = blockIdx.x * 4 + (threadIdx.x >> 6);
    if (node >= N) return;
    int lane = threadIdx.x & 63;
    int g = lane >> 3;       // 8 groups of 8 lanes
    int i = lane & 7;        // f16x8 slot within row
    int s0 = off[node], s1 = off[node + 1];
    f16x8 acc0, acc1;
    #pragma unroll
    for (int j = 0; j < 8; ++j) { acc0[j] = (_Float16)0.f; acc1[j] = (_Float16)0.f; }
    int e = s0 + g;
    for (; e + 8 < s1; e += 16) {
        f16x8 v = ((const f16x8*)x)[(size_t)adj[e] * 8 + i];
        f16x8 w = ((const f16x8*)x)[(size_t)adj[e + 8] * 8 + i];
        acc0 += v;
        acc1 += w;
    }
    if (e < s1) {
        f16x8 v = ((const f16x8*)x)[(size_t)adj[e] * 8 + i];
        acc0 += v;
    }
    float f[8];
    #pragma unroll
    for (int j = 0; j < 8; ++j) f[j] = (float)acc0[j] + (float)acc1[j];
    #pragma unroll
    for (int o = 8; o <= 32; o <<= 1) {
        #pragma unroll
        for (int j = 0; j < 8; ++j) f[j] += __shfl_xor(f[j], o, 64);
    }
    int deg = s1 - s0;
    float scale = (deg > 0) ? 1.0f / (float)deg : 0.f;
    if (g == 0) {
        f16x8 r;
        #pragma unroll
        for (int j = 0; j < 8; ++j) r[j] = (_Float16)(f[j] * scale);
        ((f16x8*)out16)[(size_t)node * 8 + i] = r;
    }
}

// ---------------- layer-1 transform via MFMA; all-f16 direct-from-global A-fragments ----------------
// res16 = f16( self + relu([mean|self] @ [wl;wr] + bl) )
__global__ __launch_bounds__(256, 6) void k_trans1_mfma(const _Float16* __restrict__ mean16,
                                                        const _Float16* __restrict__ self16,
                                                        const float* __restrict__ self,
                                                        const f16x8* __restrict__ wfrag,
                                                        const float* __restrict__ bl,
                                                        _Float16* __restrict__ res16, int N) {
    __shared__ f16x8 wf[16 * 64];            // 16 KB
    const int tid = threadIdx.x;
    for (int t = tid; t < 1024; t += 256)
        ((float4*)wf)[t] = ((const float4*)wfrag)[t];
    __syncthreads();
    const int w = tid >> 6, lane = tid & 63;
    const int g = lane >> 4, c15 = lane & 15;
    const int w16 = w * 16;
    float blv[4];
    #pragma unroll
    for (int nt = 0; nt < 4; ++nt) blv[nt] = bl[nt * 16 + c15];
    f16x8 afz;
    #pragma unroll
    for (int j = 0; j < 8; ++j) afz[j] = (_Float16)0.f;
    for (int n0 = blockIdx.x * 64; n0 < N; n0 += gridDim.x * 64) {
        int na = n0 + w16 + c15;                 // A-fragment row for this lane
        f16x8 af[4] = {afz, afz, afz, afz};
        if (na < N) {
            const _Float16* mrow = mean16 + (size_t)na * 64 + g * 8;
            const _Float16* srow = self16 + (size_t)na * 64 + g * 8;
            af[0] = *(const f16x8*)mrow;
            af[1] = *(const f16x8*)(mrow + 32);
            af[2] = *(const f16x8*)srow;
            af[3] = *(const f16x8*)(srow + 32);
        }
        f32x4 acc[4];
        #pragma unroll
        for (int nt = 0; nt < 4; ++nt) acc[nt] = f32x4{0.f, 0.f, 0.f, 0.f};
        #pragma unroll
        for (int kt = 0; kt < 4; ++kt) {
            #pragma unroll
            for (int nt = 0; nt < 4; ++nt)
                acc[nt] = __builtin_amdgcn_mfma_f32_16x16x32_f16(af[kt], wf[(kt * 4 + nt) * 64 + lane],
                                                                 acc[nt], 0, 0, 0);
        }
        #pragma unroll
        for (int nt = 0; nt < 4; ++nt) {
            #pragma unroll
            for (int r = 0; r < 4; ++r) {
                int n = n0 + w16 + g * 4 + r;
                if (n < N) {
                    size_t o = (size_t)n * 64 + nt * 16 + c15;
                    res16[o] = (_Float16)(self[o] + fmaxf(acc[nt][r] + blv[nt], 0.f));
                }
            }
        }
    }
}

// ---------------- layer-2 transform + l2norm + decoder half-projection via MFMA ----------------
// u2 = [mean16|res16] @ [wl;wr] + bl ; A = (u2/max(||u2||,1e-12)) @ wd
__global__ __launch_bounds__(256, 4) void k_trans2_mfma(const _Float16* __restrict__ mean16,
                                                        const _Float16* __restrict__ res16,
                                                        const f16x8* __restrict__ wfrag,
                                                        const f16x8* __restrict__ wdfrag,
                                                        const float* __restrict__ bl,
                                                        float* __restrict__ outA, int N) {
    __shared__ f16x8 wf[16 * 64];            // 16 KB
    __shared__ f16x8 wf2[8 * 64];            // 8 KB
    __shared__ _Float16 xs2[64][72];         // 9 KB (u2 transpose)
    const int tid = threadIdx.x;
    for (int t = tid; t < 1024; t += 256)
        ((float4*)wf)[t] = ((const float4*)wfrag)[t];
    for (int t = tid; t < 512; t += 256)
        ((float4*)wf2)[t] = ((const float4*)wdfrag)[t];
    __syncthreads();
    const int w = tid >> 6, lane = tid & 63;
    const int g = lane >> 4, c15 = lane & 15;
    const int w16 = w * 16;
    float blv[4];
    #pragma unroll
    for (int nt = 0; nt < 4; ++nt) blv[nt] = bl[nt * 16 + c15];
    f16x8 afz;
    #pragma unroll
    for (int j = 0; j < 8; ++j) afz[j] = (_Float16)0.f;
    for (int n0 = blockIdx.x * 64; n0 < N; n0 += gridDim.x * 64) {
        int na = n0 + w16 + c15;
        f16x8 af[4] = {afz, afz, afz, afz};
        if (na < N) {
            const _Float16* mrow = mean16 + (size_t)na * 64 + g * 8;
            const _Float16* rrow = res16 + (size_t)na * 64 + g * 8;
            af[0] = *(const f16x8*)mrow;
            af[1] = *(const f16x8*)(mrow + 32);
            af[2] = *(const f16x8*)rrow;
            af[3] = *(const f16x8*)(rrow + 32);
        }
        f32x4 acc[4];
        #pragma unroll
        for (int nt = 0; nt < 4; ++nt) acc[nt] = f32x4{0.f, 0.f, 0.f, 0.f};
        #pragma unroll
        for (int kt = 0; kt < 4; ++kt) {
            #pragma unroll
            for (int nt = 0; nt < 4; ++nt)
                acc[nt] = __builtin_amdgcn_mfma_f32_16x16x32_f16(af[kt], wf[(kt * 4 + nt) * 64 + lane],
                                                                 acc[nt], 0, 0, 0);
        }
        float u2[4][4];
        #pragma unroll
        for (int nt = 0; nt < 4; ++nt)
            #pragma unroll
            for (int r = 0; r < 4; ++r)
                u2[nt][r] = acc[nt][r] + blv[nt];
        float sc[4];
        #pragma unroll
        for (int r = 0; r < 4; ++r) {
            float q = u2[0][r] * u2[0][r] + u2[1][r] * u2[1][r]
                    + u2[2][r] * u2[2][r] + u2[3][r] * u2[3][r];
            q += __shfl_xor(q, 1, 64);
            q += __shfl_xor(q, 2, 64);
            q += __shfl_xor(q, 4, 64);
            q += __shfl_xor(q, 8, 64);
            sc[r] = 1.f / fmaxf(sqrtf(q), 1e-12f);
        }
        #pragma unroll
        for (int nt = 0; nt < 4; ++nt)
            #pragma unroll
            for (int r = 0; r < 4; ++r)
                xs2[w16 + g * 4 + r][nt * 16 + c15] = (_Float16)(u2[nt][r] * sc[r]);
        f32x4 acc2[4];
        #pragma unroll
        for (int nt = 0; nt < 4; ++nt) acc2[nt] = f32x4{0.f, 0.f, 0.f, 0.f};
        #pragma unroll
        for (int kt = 0; kt < 2; ++kt) {
            f16x8 af2 = *(const f16x8*)&xs2[w16 + c15][kt * 32 + (g << 3)];
            #pragma unroll
            for (int nt = 0; nt < 4; ++nt)
                acc2[nt] = __builtin_amdgcn_mfma_f32_16x16x32_f16(af2, wf2[(kt * 4 + nt) * 64 + lane],
                                                                  acc2[nt], 0, 0, 0);
        }
        #pragma unroll
        for (int nt = 0; nt < 4; ++nt) {
            #pragma unroll
            for (int r = 0; r < 4; ++r) {
                int n = n0 + w16 + g * 4 + r;
                if (n < N)
                    outA[(size_t)n * 64 + nt * 16 + c15] = acc2[nt][r];
            }
        }
    }
}

// ---------------- decoder: out = relu(A[ls]+B[ld]+b1) . w2 + b2  (4 edges/wave) ----------------
__global__ __launch_bounds__(256) void k_dec(const float* __restrict__ A,
                                             const float* __restrict__ B,
                                             const int* __restrict__ ls,
                                             const int* __restrict__ ld,
                                             const float* __restrict__ b1,
                                             const float* __restrict__ w2,
                                             const float* __restrict__ b2,
                                             float* __restrict__ out, int EL) {
    int lane = threadIdx.x & 63;
    int g = lane >> 4, i = lane & 15;
    int e = blockIdx.x * 16 + (threadIdx.x >> 6) * 4 + g;
    if (e >= EL) return;
    int u = ls[e], m = ld[e];
    float4 av  = ((const float4*)A)[(size_t)u * 16 + i];
    float4 bv  = ((const float4*)B)[(size_t)m * 16 + i];
    float4 b1v = ((const float4*)b1)[i];
    float4 w2v = ((const float4*)w2)[i];
    float p = fmaxf(av.x + bv.x + b1v.x, 0.f) * w2v.x
            + fmaxf(av.y + bv.y + b1v.y, 0.f) * w2v.y
            + fmaxf(av.z + bv.z + b1v.z, 0.f) * w2v.z
            + fmaxf(av.w + bv.w + b1v.w, 0.f) * w2v.w;
    #pragma unroll
    for (int o = 1; o <= 8; o <<= 1) p += __shfl_xor(p, o, 64);
    if (i == 0) out[e] = p + b2[0];
}

extern "C" void kernel_launch(void* const* d_in, const int* in_sizes, int n_in,
                              void* d_out, int out_size, void* d_ws, size_t ws_size,
                              hipStream_t stream) {
    const float* movie_x  = (const float*)d_in[0];
    const float* user_emb = (const float*)d_in[1];
    const float* proj_w   = (const float*)d_in[2];
    const float* proj_b   = (const float*)d_in[3];
    const float* c1_um_wl = (const float*)d_in[4];
    const float* c1_um_bl = (const float*)d_in[5];
    const float* c1_um_wr = (const float*)d_in[6];
    const float* c1_mu_wl = (const float*)d_in[7];
    const float* c1_mu_bl = (const float*)d_in[8];
    const float* c1_mu_wr = (const float*)d_in[9];
    const float* c2_um_wl = (const float*)d_in[10];
    const float* c2_um_bl = (const float*)d_in[11];
    const float* c2_um_wr = (const float*)d_in[12];
    const float* c2_mu_wl = (const float*)d_in[13];
    const float* c2_mu_bl = (const float*)d_in[14];
    const float* c2_mu_wr = (const float*)d_in[15];
    const float* dec_w1   = (const float*)d_in[16];
    const float* dec_b1   = (const float*)d_in[17];
    const float* dec_w2   = (const float*)d_in[18];
    const float* dec_b2   = (const float*)d_in[19];
    const int* edge_src = (const int*)d_in[20];
    const int* edge_dst = (const int*)d_in[21];
    const int* lbl_src  = (const int*)d_in[22];
    const int* lbl_dst  = (const int*)d_in[23];

    const int M  = in_sizes[0] / 256;
    const int U  = in_sizes[1] / 64;
    const int E  = in_sizes[20];
    const int EL = in_sizes[22];
    float* out = (float*)d_out;

    char* ws = (char*)d_ws;
    size_t off = 0;
    auto alloc = [&](size_t bytes) -> void* {
        off = (off + 255) & ~(size_t)255;
        void* p = ws + off;
        off += bytes;
        return p;
    };
    int* bsums  = (int*)alloc(1024);
    int* off_u  = (int*)alloc((size_t)(U + 1) * 4);
    int* off_m  = (int*)alloc((size_t)(M + 1) * 4);
    int* adj_u  = (int*)alloc((size_t)E * 4);
    int* adj_m  = (int*)alloc((size_t)E * 4);
    f16x8* wtab = (f16x8*)alloc(5120 * 16);                  // 80 KB fragment tables
    float* movie0 = (float*)alloc((size_t)M * 64 * 4);       // fp32, later reused as B
    _Float16* movie16 = (_Float16*)alloc((size_t)M * 64 * 2);
    _Float16* user16  = (_Float16*)alloc((size_t)U * 64 * 2);
    float* mean_m = (float*)alloc((size_t)M * 64 * 4);       // sort scratch + unused fp32
    float* mean_u = (float*)alloc((size_t)U * 64 * 4);       // sort tmp alias + decoder A out
    _Float16* mean16_m = (_Float16*)alloc((size_t)M * 64 * 2);
    _Float16* mean16_u = (_Float16*)alloc((size_t)U * 64 * 2);
    _Float16* m_res16 = (_Float16*)alloc((size_t)M * 64 * 2);
    _Float16* u_res16 = (_Float16*)alloc((size_t)U * 64 * 2);

    f16x8* wf1m = wtab;            // [c1_um_wl; c1_um_wr]
    f16x8* wf1u = wtab + 1024;     // [c1_mu_wl; c1_mu_wr]
    f16x8* wf2m = wtab + 2048;     // [c2_um_wl; c2_um_wr]
    f16x8* wf2u = wtab + 3072;     // [c2_mu_wl; c2_mu_wr]
    f16x8* wdm  = wtab + 4096;     // dec_w1 bottom half (movie B)
    f16x8* wdu  = wtab + 4608;     // dec_w1 top half (user A)

    // CSR-build scratch aliases (all dead before mean buffers first written):
    int*  hist_u   = (int*)mean_m;            // ND*NB ints = 256 KB
    int*  hist_m   = hist_u + ND * NB;        // 256 KB
    int*  scanned  = hist_m + ND * NB;        // 256 KB
    int*  off_flat = scanned + ND * NB;       // ND*NB+1 ints
    int2* tmp      = (int2*)mean_u;           // E*8 = 16 MB (< 25.6 MB)

    auto cdiv = [](int a, int b) { return (a + b - 1) / b; };
    const int chunk = cdiv(E, NB);
    const int NF = ND * NB;                   // 65536 flat counters

    hipMemsetAsync(hist_u, 0, (size_t)NF * 4, stream);
    hipMemsetAsync(hist_m, 0, (size_t)NF * 4, stream);
    k_hist2<<<NB, 256, 0, stream>>>(edge_src, edge_dst, hist_u, hist_m, E, chunk);

    // one-time weight fragment tables + f16 user table
    k_wprep128<<<4, 256, 0, stream>>>(c1_um_wl, c1_um_wr, wf1m);
    k_wprep128<<<4, 256, 0, stream>>>(c1_mu_wl, c1_mu_wr, wf1u);
    k_wprep128<<<4, 256, 0, stream>>>(c2_um_wl, c2_um_wr, wf2m);
    k_wprep128<<<4, 256, 0, stream>>>(c2_mu_wl, c2_mu_wr, wf2u);
    k_wprep64<<<2, 256, 0, stream>>>(dec_w1 + 64 * 64, wdm);
    k_wprep64<<<2, 256, 0, stream>>>(dec_w1, wdu);
    k_cvt<<<cdiv(U * 16, 256), 256, 0, stream>>>(user_emb, user16, U * 16);

    // movie-side CSR (bucket by dst>>7, width 128)
    k_scan_local<<<NF / 1024, 256, 0, stream>>>(hist_m, scanned, bsums, NF);
    k_scan_carry<<<1, 256, 0, stream>>>(bsums, NF / 1024);
    k_scan_off<<<cdiv(NF + 1, 256), 256, 0, stream>>>(scanned, bsums, off_flat, NF);
    k_scatter<<<NB, 256, 0, stream>>>(edge_dst, edge_src, off_flat, tmp, E, chunk, 7);
    k_bucket<128><<<ND, 256, 0, stream>>>(tmp, off_flat, adj_m, off_m, E, 7, M);

    // user-side CSR (bucket by src>>9, width 512)
    k_scan_local<<<NF / 1024, 256, 0, stream>>>(hist_u, scanned, bsums, NF);
    k_scan_carry<<<1, 256, 0, stream>>>(bsums, NF / 1024);
    k_scan_off<<<cdiv(NF + 1, 256), 256, 0, stream>>>(scanned, bsums, off_flat, NF);
    k_scatter<<<NB, 256, 0, stream>>>(edge_src, edge_dst, off_flat, tmp, E, chunk, 9);
    k_bucket<512><<<ND, 256, 0, stream>>>(tmp, off_flat, adj_u, off_u, E, 9, U);

    k_proj<<<cdiv(M, 16), 256, 0, stream>>>(movie_x, proj_w, proj_b, movie0, movie16, M);

    int gm = min(cdiv(M, 64), 2048);
    int gu = min(cdiv(U, 64), 2048);

    // layer 1 (gathers over f16 tables -> f16 means)
    k_agg_h<<<cdiv(M, 4), 256, 0, stream>>>(user16, adj_m, off_m, mean16_m, M);
    k_agg_h<<<cdiv(U, 4), 256, 0, stream>>>(movie16, adj_u, off_u, mean16_u, U);
    k_trans1_mfma<<<gm, 256, 0, stream>>>(mean16_m, movie16, movie0, wf1m, c1_um_bl, m_res16, M);
    k_trans1_mfma<<<gu, 256, 0, stream>>>(mean16_u, user16, user_emb, wf1u, c1_mu_bl, u_res16, U);

    // layer 2 (gathers over f16 residuals -> f16 means)
    k_agg_h<<<cdiv(M, 4), 256, 0, stream>>>(u_res16, adj_m, off_m, mean16_m, M);
    k_agg_h<<<cdiv(U, 4), 256, 0, stream>>>(m_res16, adj_u, off_u, mean16_u, U);
    // B = l2norm(m2) @ W1_bot   (into movie0 buffer)
    k_trans2_mfma<<<gm, 256, 0, stream>>>(mean16_m, m_res16, wf2m, wdm, c2_um_bl, movie0, M);
    // A = l2norm(u2) @ W1_top   (into mean_u fp32 buffer)
    k_trans2_mfma<<<gu, 256, 0, stream>>>(mean16_u, u_res16, wf2u, wdu, c2_mu_bl, mean_u, U);

    // decoder
    k_dec<<<cdiv(EL, 16), 256, 0, stream>>>(mean_u, movie0, lbl_src, lbl_dst,
                                            dec_b1, dec_w2, dec_b2, out, EL);
}

// Round 15
// 426.342 us; speedup vs baseline: 1.1142x; 1.0502x over previous
//
#include <hip/hip_runtime.h>

#define NB 256   // blocks for hist/scatter passes
#define ND 256   // digit buckets

typedef _Float16 f16x8 __attribute__((ext_vector_type(8)));
typedef _Float16 f16x4 __attribute__((ext_vector_type(4)));
typedef _Float16 f16x2 __attribute__((ext_vector_type(2)));
typedef float f32x4 __attribute__((ext_vector_type(4)));

__device__ inline f16x8 cvt8(float4 a, float4 b) {
    return f16x8{(_Float16)a.x, (_Float16)a.y, (_Float16)a.z, (_Float16)a.w,
                 (_Float16)b.x, (_Float16)b.y, (_Float16)b.z, (_Float16)b.w};
}

// ---------------- fp32 -> fp16 row conversion ----------------
__global__ __launch_bounds__(256) void k_cvt(const float* __restrict__ in,
                                             _Float16* __restrict__ out, int n4) {
    int i = blockIdx.x * 256 + threadIdx.x;
    if (i < n4) {
        float4 v = ((const float4*)in)[i];
        ((f16x4*)out)[i] = f16x4{(_Float16)v.x, (_Float16)v.y, (_Float16)v.z, (_Float16)v.w};
    }
}

// ---------------- one-time weight fragment builders ----------------
__global__ __launch_bounds__(256) void k_wprep128(const float* __restrict__ wl,
                                                  const float* __restrict__ wr,
                                                  f16x8* __restrict__ out) {
    int idx = blockIdx.x * 256 + threadIdx.x;   // 0..1023
    int lane_i = idx & 63, t = idx >> 6;
    int kt = t >> 2, nt = t & 3;
    int col = nt * 16 + (lane_i & 15);
    int krow = kt * 32 + ((lane_i >> 4) << 3);
    f16x8 v;
    #pragma unroll
    for (int j = 0; j < 8; ++j) {
        int k = krow + j;
        const float* W = (k < 64) ? (wl + (size_t)k * 64) : (wr + (size_t)(k - 64) * 64);
        v[j] = (_Float16)W[col];
    }
    out[t * 64 + lane_i] = v;
}

__global__ __launch_bounds__(256) void k_wprep64(const float* __restrict__ wd,
                                                 f16x8* __restrict__ out) {
    int idx = blockIdx.x * 256 + threadIdx.x;   // 0..511
    int lane_i = idx & 63, t = idx >> 6;
    int col = (t & 3) * 16 + (lane_i & 15);
    int krow = (t >> 2) * 32 + ((lane_i >> 4) << 3);
    f16x8 v;
    #pragma unroll
    for (int j = 0; j < 8; ++j)
        v[j] = (_Float16)wd[(size_t)(krow + j) * 64 + col];
    out[t * 64 + lane_i] = v;
}

// 256x64 -> 2048 f16x8 fragments (grid 8 x 256)
__global__ __launch_bounds__(256) void k_wprep256(const float* __restrict__ wd,
                                                  f16x8* __restrict__ out) {
    int idx = blockIdx.x * 256 + threadIdx.x;   // 0..2047
    int lane_i = idx & 63, t = idx >> 6;        // t = kt*4+nt, kt 0..7
    int col = (t & 3) * 16 + (lane_i & 15);
    int krow = (t >> 2) * 32 + ((lane_i >> 4) << 3);
    f16x8 v;
    #pragma unroll
    for (int j = 0; j < 8; ++j)
        v[j] = (_Float16)wd[(size_t)(krow + j) * 64 + col];
    out[t * 64 + lane_i] = v;
}

// ---------------- pass A: per-block digit histograms for BOTH sides ----------------
__global__ __launch_bounds__(256) void k_hist2(const int* __restrict__ src, const int* __restrict__ dst,
                                               int* __restrict__ hist_u, int* __restrict__ hist_m,
                                               int E, int chunk) {
    __shared__ int hu[ND], hm[ND];
    for (int t = threadIdx.x; t < ND; t += 256) { hu[t] = 0; hm[t] = 0; }
    __syncthreads();
    int b = blockIdx.x;
    int e0 = b * chunk, e1 = min(E, e0 + chunk);
    for (int e = e0 + threadIdx.x; e < e1; e += 256) {
        atomicAdd(&hu[src[e] >> 9], 1);
        atomicAdd(&hm[dst[e] >> 7], 1);
    }
    __syncthreads();
    for (int t = threadIdx.x; t < ND; t += 256) {
        hist_u[t * NB + b] = hu[t];
        hist_m[t * NB + b] = hm[t];
    }
}

// ---------------- 2-level inclusive scan -> exclusive offsets ----------------
__global__ void k_scan_local(const int* __restrict__ deg, int* __restrict__ scanned,
                             int* __restrict__ bsums, int N) {
    __shared__ int s[1024];
    int base = blockIdx.x * 1024;
    for (int t = threadIdx.x; t < 1024; t += 256) {
        int i = base + t;
        s[t] = (i < N) ? deg[i] : 0;
    }
    __syncthreads();
    for (int d = 1; d < 1024; d <<= 1) {
        int vals[4];
        for (int j = 0; j < 4; ++j) {
            int t = threadIdx.x + j * 256;
            vals[j] = (t >= d) ? s[t - d] : 0;
        }
        __syncthreads();
        for (int j = 0; j < 4; ++j) {
            int t = threadIdx.x + j * 256;
            s[t] += vals[j];
        }
        __syncthreads();
    }
    for (int t = threadIdx.x; t < 1024; t += 256) {
        int i = base + t;
        if (i < N) scanned[i] = s[t];
    }
    if (threadIdx.x == 0) bsums[blockIdx.x] = s[1023];
}

__global__ void k_scan_carry(int* bsums, int nb) {
    __shared__ int s[256];
    int t = threadIdx.x;
    s[t] = (t < nb) ? bsums[t] : 0;
    __syncthreads();
    for (int d = 1; d < 256; d <<= 1) {
        int v = (t >= d) ? s[t - d] : 0;
        __syncthreads();
        s[t] += v;
        __syncthreads();
    }
    if (t < nb) bsums[t] = s[t];
}

__global__ void k_scan_off(const int* __restrict__ scanned, const int* __restrict__ bsums,
                           int* __restrict__ off, int N) {
    int i = blockIdx.x * 256 + threadIdx.x;
    if (i > N) return;
    int v = 0;
    if (i > 0) {
        int j = i - 1;
        int b = j >> 10;
        v = scanned[j] + (b > 0 ? bsums[b - 1] : 0);
    }
    off[i] = v;
}

// ---------------- pass A scatter: partition edges by top digit (no global atomics) ----------------
__global__ __launch_bounds__(256) void k_scatter(const int* __restrict__ key, const int* __restrict__ val,
                                                 const int* __restrict__ off_flat, int2* __restrict__ tmp,
                                                 int E, int chunk, int shift) {
    __shared__ int cnt[ND];
    for (int t = threadIdx.x; t < ND; t += 256) cnt[t] = 0;
    __syncthreads();
    int b = blockIdx.x;
    int e0 = b * chunk, e1 = min(E, e0 + chunk);
    for (int e = e0 + threadIdx.x; e < e1; e += 256) {
        int k = key[e];
        int d = k >> shift;
        int r = atomicAdd(&cnt[d], 1);           // LDS-only rank
        tmp[off_flat[d * NB + b] + r] = make_int2(k, val[e]);
    }
}

// ---------------- pass B: per-bucket counting sort -> adj + node offsets ----------------
template <int WIDTH>
__global__ __launch_bounds__(256) void k_bucket(const int2* __restrict__ tmp,
                                                const int* __restrict__ off_flat,
                                                int* __restrict__ adj, int* __restrict__ off_node,
                                                int E, int shift, int NN) {
    __shared__ int cnt[WIDTH];
    int d = blockIdx.x;
    int bstart = off_flat[d * NB];
    int bend   = off_flat[(d + 1) * NB];
    for (int t = threadIdx.x; t < WIDTH; t += 256) cnt[t] = 0;
    __syncthreads();
    int bsz = bend - bstart;
    for (int i = threadIdx.x; i < bsz; i += 256)
        atomicAdd(&cnt[tmp[bstart + i].x & (WIDTH - 1)], 1);
    __syncthreads();
    int lane = threadIdx.x;
    if (lane < 64) {
        constexpr int EPL = WIDTH >> 6;
        int vals[EPL];
        int tot = 0;
        #pragma unroll
        for (int j = 0; j < EPL; ++j) { vals[j] = cnt[lane * EPL + j]; tot += vals[j]; }
        int inc = tot;
        #pragma unroll
        for (int o = 1; o < 64; o <<= 1) {
            int tsh = __shfl_up(inc, o, 64);
            if (lane >= o) inc += tsh;
        }
        int ex = inc - tot;
        #pragma unroll
        for (int j = 0; j < EPL; ++j) { cnt[lane * EPL + j] = ex; ex += vals[j]; }
    }
    __syncthreads();
    int base_node = d << shift;
    for (int t = threadIdx.x; t < WIDTH; t += 256) {
        int node = base_node + t;
        if (node < NN) off_node[node] = bstart + cnt[t];
    }
    if (d == 0 && threadIdx.x == 0) off_node[NN] = E;
    __syncthreads();
    for (int i = threadIdx.x; i < bsz; i += 256) {
        int2 e = tmp[bstart + i];
        int r = atomicAdd(&cnt[e.x & (WIDTH - 1)], 1);
        adj[bstart + r] = e.y;
    }
}

// ---------------- movie projection via MFMA: relu(movie_x @ proj_w + b) ----------------
// A-fragments direct from global movie_x rows; fp32 + f16 outputs.
__global__ __launch_bounds__(256, 4) void k_proj_mfma(const float* __restrict__ mx,
                                                      const f16x8* __restrict__ wfrag,
                                                      const float* __restrict__ b,
                                                      float* __restrict__ out,
                                                      _Float16* __restrict__ out16, int M) {
    __shared__ f16x8 wf[32 * 64];            // 32 KB (K=256 -> 8 kt x 4 nt)
    const int tid = threadIdx.x;
    for (int t = tid; t < 2048; t += 256)
        ((float4*)wf)[t] = ((const float4*)wfrag)[t];
    __syncthreads();
    const int w = tid >> 6, lane = tid & 63;
    const int g = lane >> 4, c15 = lane & 15;
    const int w16 = w * 16;
    float blv[4];
    #pragma unroll
    for (int nt = 0; nt < 4; ++nt) blv[nt] = b[nt * 16 + c15];
    f16x8 afz;
    #pragma unroll
    for (int j = 0; j < 8; ++j) afz[j] = (_Float16)0.f;
    for (int n0 = blockIdx.x * 64; n0 < M; n0 += gridDim.x * 64) {
        int na = n0 + w16 + c15;
        f32x4 acc[4];
        #pragma unroll
        for (int nt = 0; nt < 4; ++nt) acc[nt] = f32x4{0.f, 0.f, 0.f, 0.f};
        #pragma unroll
        for (int kt = 0; kt < 8; ++kt) {
            f16x8 af = afz;
            if (na < M) {
                const float* row = mx + (size_t)na * 256 + kt * 32 + g * 8;
                af = cvt8(*(const float4*)row, *(const float4*)(row + 4));
            }
            #pragma unroll
            for (int nt = 0; nt < 4; ++nt)
                acc[nt] = __builtin_amdgcn_mfma_f32_16x16x32_f16(af, wf[(kt * 4 + nt) * 64 + lane],
                                                                 acc[nt], 0, 0, 0);
        }
        #pragma unroll
        for (int nt = 0; nt < 4; ++nt) {
            #pragma unroll
            for (int r = 0; r < 4; ++r) {
                int n = n0 + w16 + g * 4 + r;
                if (n < M) {
                    float v = fmaxf(acc[nt][r] + blv[nt], 0.f);
                    size_t o = (size_t)n * 64 + nt * 16 + c15;
                    out[o] = v;
                    out16[o] = (_Float16)v;
                }
            }
        }
    }
}

// ---------------- gather-side segment mean, packed-f16 accumulate; f16 mean output ----------------
__global__ __launch_bounds__(256) void k_agg_h(const _Float16* __restrict__ x,
                                               const int* __restrict__ adj,
                                               const int* __restrict__ off,
                                               _Float16* __restrict__ out16, int N) {
    int node = blockIdx.x * 4 + (threadIdx.x >> 6);
    if (node >= N) return;
    int lane = threadIdx.x & 63;
    int g = lane >> 3;       // 8 groups of 8 lanes
    int i = lane & 7;        // f16x8 slot within row
    int s0 = off[node], s1 = off[node + 1];
    f16x8 acc0, acc1;
    #pragma unroll
    for (int j = 0; j < 8; ++j) { acc0[j] = (_Float16)0.f; acc1[j] = (_Float16)0.f; }
    int e = s0 + g;
    for (; e + 8 < s1; e += 16) {
        f16x8 v = ((const f16x8*)x)[(size_t)adj[e] * 8 + i];
        f16x8 w = ((const f16x8*)x)[(size_t)adj[e + 8] * 8 + i];
        acc0 += v;
        acc1 += w;
    }
    if (e < s1) {
        f16x8 v = ((const f16x8*)x)[(size_t)adj[e] * 8 + i];
        acc0 += v;
    }
    float f[8];
    #pragma unroll
    for (int j = 0; j < 8; ++j) f[j] = (float)acc0[j] + (float)acc1[j];
    #pragma unroll
    for (int o = 8; o <= 32; o <<= 1) {
        #pragma unroll
        for (int j = 0; j < 8; ++j) f[j] += __shfl_xor(f[j], o, 64);
    }
    int deg = s1 - s0;
    float scale = (deg > 0) ? 1.0f / (float)deg : 0.f;
    if (g == 0) {
        f16x8 r;
        #pragma unroll
        for (int j = 0; j < 8; ++j) r[j] = (_Float16)(f[j] * scale);
        ((f16x8*)out16)[(size_t)node * 8 + i] = r;
    }
}

// ---------------- layer-1 transform via MFMA; all-f16 direct-from-global A-fragments ----------------
// res16 = f16( self + relu([mean|self] @ [wl;wr] + bl) )
__global__ __launch_bounds__(256, 6) void k_trans1_mfma(const _Float16* __restrict__ mean16,
                                                        const _Float16* __restrict__ self16,
                                                        const float* __restrict__ self,
                                                        const f16x8* __restrict__ wfrag,
                                                        const float* __restrict__ bl,
                                                        _Float16* __restrict__ res16, int N) {
    __shared__ f16x8 wf[16 * 64];            // 16 KB
    const int tid = threadIdx.x;
    for (int t = tid; t < 1024; t += 256)
        ((float4*)wf)[t] = ((const float4*)wfrag)[t];
    __syncthreads();
    const int w = tid >> 6, lane = tid & 63;
    const int g = lane >> 4, c15 = lane & 15;
    const int w16 = w * 16;
    float blv[4];
    #pragma unroll
    for (int nt = 0; nt < 4; ++nt) blv[nt] = bl[nt * 16 + c15];
    f16x8 afz;
    #pragma unroll
    for (int j = 0; j < 8; ++j) afz[j] = (_Float16)0.f;
    for (int n0 = blockIdx.x * 64; n0 < N; n0 += gridDim.x * 64) {
        int na = n0 + w16 + c15;                 // A-fragment row for this lane
        f16x8 af[4] = {afz, afz, afz, afz};
        if (na < N) {
            const _Float16* mrow = mean16 + (size_t)na * 64 + g * 8;
            const _Float16* srow = self16 + (size_t)na * 64 + g * 8;
            af[0] = *(const f16x8*)mrow;
            af[1] = *(const f16x8*)(mrow + 32);
            af[2] = *(const f16x8*)srow;
            af[3] = *(const f16x8*)(srow + 32);
        }
        f32x4 acc[4];
        #pragma unroll
        for (int nt = 0; nt < 4; ++nt) acc[nt] = f32x4{0.f, 0.f, 0.f, 0.f};
        #pragma unroll
        for (int kt = 0; kt < 4; ++kt) {
            #pragma unroll
            for (int nt = 0; nt < 4; ++nt)
                acc[nt] = __builtin_amdgcn_mfma_f32_16x16x32_f16(af[kt], wf[(kt * 4 + nt) * 64 + lane],
                                                                 acc[nt], 0, 0, 0);
        }
        #pragma unroll
        for (int nt = 0; nt < 4; ++nt) {
            #pragma unroll
            for (int r = 0; r < 4; ++r) {
                int n = n0 + w16 + g * 4 + r;
                if (n < N) {
                    size_t o = (size_t)n * 64 + nt * 16 + c15;
                    res16[o] = (_Float16)(self[o] + fmaxf(acc[nt][r] + blv[nt], 0.f));
                }
            }
        }
    }
}

// ---------------- layer-2 transform + l2norm + decoder half-projection via MFMA ----------------
// u2 = [mean16|res16] @ [wl;wr] + bl ; A = (u2/max(||u2||,1e-12)) @ wd
__global__ __launch_bounds__(256, 4) void k_trans2_mfma(const _Float16* __restrict__ mean16,
                                                        const _Float16* __restrict__ res16,
                                                        const f16x8* __restrict__ wfrag,
                                                        const f16x8* __restrict__ wdfrag,
                                                        const float* __restrict__ bl,
                                                        float* __restrict__ outA, int N) {
    __shared__ f16x8 wf[16 * 64];            // 16 KB
    __shared__ f16x8 wf2[8 * 64];            // 8 KB
    __shared__ _Float16 xs2[64][72];         // 9 KB (u2 transpose)
    const int tid = threadIdx.x;
    for (int t = tid; t < 1024; t += 256)
        ((float4*)wf)[t] = ((const float4*)wfrag)[t];
    for (int t = tid; t < 512; t += 256)
        ((float4*)wf2)[t] = ((const float4*)wdfrag)[t];
    __syncthreads();
    const int w = tid >> 6, lane = tid & 63;
    const int g = lane >> 4, c15 = lane & 15;
    const int w16 = w * 16;
    float blv[4];
    #pragma unroll
    for (int nt = 0; nt < 4; ++nt) blv[nt] = bl[nt * 16 + c15];
    f16x8 afz;
    #pragma unroll
    for (int j = 0; j < 8; ++j) afz[j] = (_Float16)0.f;
    for (int n0 = blockIdx.x * 64; n0 < N; n0 += gridDim.x * 64) {
        int na = n0 + w16 + c15;
        f16x8 af[4] = {afz, afz, afz, afz};
        if (na < N) {
            const _Float16* mrow = mean16 + (size_t)na * 64 + g * 8;
            const _Float16* rrow = res16 + (size_t)na * 64 + g * 8;
            af[0] = *(const f16x8*)mrow;
            af[1] = *(const f16x8*)(mrow + 32);
            af[2] = *(const f16x8*)rrow;
            af[3] = *(const f16x8*)(rrow + 32);
        }
        f32x4 acc[4];
        #pragma unroll
        for (int nt = 0; nt < 4; ++nt) acc[nt] = f32x4{0.f, 0.f, 0.f, 0.f};
        #pragma unroll
        for (int kt = 0; kt < 4; ++kt) {
            #pragma unroll
            for (int nt = 0; nt < 4; ++nt)
                acc[nt] = __builtin_amdgcn_mfma_f32_16x16x32_f16(af[kt], wf[(kt * 4 + nt) * 64 + lane],
                                                                 acc[nt], 0, 0, 0);
        }
        float u2[4][4];
        #pragma unroll
        for (int nt = 0; nt < 4; ++nt)
            #pragma unroll
            for (int r = 0; r < 4; ++r)
                u2[nt][r] = acc[nt][r] + blv[nt];
        float sc[4];
        #pragma unroll
        for (int r = 0; r < 4; ++r) {
            float q = u2[0][r] * u2[0][r] + u2[1][r] * u2[1][r]
                    + u2[2][r] * u2[2][r] + u2[3][r] * u2[3][r];
            q += __shfl_xor(q, 1, 64);
            q += __shfl_xor(q, 2, 64);
            q += __shfl_xor(q, 4, 64);
            q += __shfl_xor(q, 8, 64);
            sc[r] = 1.f / fmaxf(sqrtf(q), 1e-12f);
        }
        #pragma unroll
        for (int nt = 0; nt < 4; ++nt)
            #pragma unroll
            for (int r = 0; r < 4; ++r)
                xs2[w16 + g * 4 + r][nt * 16 + c15] = (_Float16)(u2[nt][r] * sc[r]);
        f32x4 acc2[4];
        #pragma unroll
        for (int nt = 0; nt < 4; ++nt) acc2[nt] = f32x4{0.f, 0.f, 0.f, 0.f};
        #pragma unroll
        for (int kt = 0; kt < 2; ++kt) {
            f16x8 af2 = *(const f16x8*)&xs2[w16 + c15][kt * 32 + (g << 3)];
            #pragma unroll
            for (int nt = 0; nt < 4; ++nt)
                acc2[nt] = __builtin_amdgcn_mfma_f32_16x16x32_f16(af2, wf2[(kt * 4 + nt) * 64 + lane],
                                                                  acc2[nt], 0, 0, 0);
        }
        #pragma unroll
        for (int nt = 0; nt < 4; ++nt) {
            #pragma unroll
            for (int r = 0; r < 4; ++r) {
                int n = n0 + w16 + g * 4 + r;
                if (n < N)
                    outA[(size_t)n * 64 + nt * 16 + c15] = acc2[nt][r];
            }
        }
    }
}

// ---------------- decoder: out = relu(A[ls]+B[ld]+b1) . w2 + b2  (4 edges/wave) ----------------
__global__ __launch_bounds__(256) void k_dec(const float* __restrict__ A,
                                             const float* __restrict__ B,
                                             const int* __restrict__ ls,
                                             const int* __restrict__ ld,
                                             const float* __restrict__ b1,
                                             const float* __restrict__ w2,
                                             const float* __restrict__ b2,
                                             float* __restrict__ out, int EL) {
    int lane = threadIdx.x & 63;
    int g = lane >> 4, i = lane & 15;
    int e = blockIdx.x * 16 + (threadIdx.x >> 6) * 4 + g;
    if (e >= EL) return;
    int u = ls[e], m = ld[e];
    float4 av  = ((const float4*)A)[(size_t)u * 16 + i];
    float4 bv  = ((const float4*)B)[(size_t)m * 16 + i];
    float4 b1v = ((const float4*)b1)[i];
    float4 w2v = ((const float4*)w2)[i];
    float p = fmaxf(av.x + bv.x + b1v.x, 0.f) * w2v.x
            + fmaxf(av.y + bv.y + b1v.y, 0.f) * w2v.y
            + fmaxf(av.z + bv.z + b1v.z, 0.f) * w2v.z
            + fmaxf(av.w + bv.w + b1v.w, 0.f) * w2v.w;
    #pragma unroll
    for (int o = 1; o <= 8; o <<= 1) p += __shfl_xor(p, o, 64);
    if (i == 0) out[e] = p + b2[0];
}

extern "C" void kernel_launch(void* const* d_in, const int* in_sizes, int n_in,
                              void* d_out, int out_size, void* d_ws, size_t ws_size,
                              hipStream_t stream) {
    const float* movie_x  = (const float*)d_in[0];
    const float* user_emb = (const float*)d_in[1];
    const float* proj_w   = (const float*)d_in[2];
    const float* proj_b   = (const float*)d_in[3];
    const float* c1_um_wl = (const float*)d_in[4];
    const float* c1_um_bl = (const float*)d_in[5];
    const float* c1_um_wr = (const float*)d_in[6];
    const float* c1_mu_wl = (const float*)d_in[7];
    const float* c1_mu_bl = (const float*)d_in[8];
    const float* c1_mu_wr = (const float*)d_in[9];
    const float* c2_um_wl = (const float*)d_in[10];
    const float* c2_um_bl = (const float*)d_in[11];
    const float* c2_um_wr = (const float*)d_in[12];
    const float* c2_mu_wl = (const float*)d_in[13];
    const float* c2_mu_bl = (const float*)d_in[14];
    const float* c2_mu_wr = (const float*)d_in[15];
    const float* dec_w1   = (const float*)d_in[16];
    const float* dec_b1   = (const float*)d_in[17];
    const float* dec_w2   = (const float*)d_in[18];
    const float* dec_b2   = (const float*)d_in[19];
    const int* edge_src = (const int*)d_in[20];
    const int* edge_dst = (const int*)d_in[21];
    const int* lbl_src  = (const int*)d_in[22];
    const int* lbl_dst  = (const int*)d_in[23];

    const int M  = in_sizes[0] / 256;
    const int U  = in_sizes[1] / 64;
    const int E  = in_sizes[20];
    const int EL = in_sizes[22];
    float* out = (float*)d_out;

    char* ws = (char*)d_ws;
    size_t off = 0;
    auto alloc = [&](size_t bytes) -> void* {
        off = (off + 255) & ~(size_t)255;
        void* p = ws + off;
        off += bytes;
        return p;
    };
    int* bsums  = (int*)alloc(1024);
    int* off_u  = (int*)alloc((size_t)(U + 1) * 4);
    int* off_m  = (int*)alloc((size_t)(M + 1) * 4);
    int* adj_u  = (int*)alloc((size_t)E * 4);
    int* adj_m  = (int*)alloc((size_t)E * 4);
    f16x8* wtab = (f16x8*)alloc(7168 * 16);                  // 112 KB fragment tables
    float* movie0 = (float*)alloc((size_t)M * 64 * 4);       // fp32, later reused as B
    _Float16* movie16 = (_Float16*)alloc((size_t)M * 64 * 2);
    _Float16* user16  = (_Float16*)alloc((size_t)U * 64 * 2);
    float* mean_m = (float*)alloc((size_t)M * 64 * 4);       // sort scratch
    float* mean_u = (float*)alloc((size_t)U * 64 * 4);       // sort tmp alias + decoder A out
    _Float16* mean16_m = (_Float16*)alloc((size_t)M * 64 * 2);
    _Float16* mean16_u = (_Float16*)alloc((size_t)U * 64 * 2);
    _Float16* m_res16 = (_Float16*)alloc((size_t)M * 64 * 2);
    _Float16* u_res16 = (_Float16*)alloc((size_t)U * 64 * 2);

    f16x8* wf1m = wtab;            // [c1_um_wl; c1_um_wr]
    f16x8* wf1u = wtab + 1024;     // [c1_mu_wl; c1_mu_wr]
    f16x8* wf2m = wtab + 2048;     // [c2_um_wl; c2_um_wr]
    f16x8* wf2u = wtab + 3072;     // [c2_mu_wl; c2_mu_wr]
    f16x8* wdm  = wtab + 4096;     // dec_w1 bottom half (movie B)
    f16x8* wdu  = wtab + 4608;     // dec_w1 top half (user A)
    f16x8* wpj  = wtab + 5120;     // proj_w (256x64), 2048 fragments

    // CSR-build scratch aliases (all dead before mean buffers first written):
    int*  hist_u   = (int*)mean_m;            // ND*NB ints = 256 KB
    int*  hist_m   = hist_u + ND * NB;        // 256 KB
    int*  scanned  = hist_m + ND * NB;        // 256 KB
    int*  off_flat = scanned + ND * NB;       // ND*NB+1 ints
    int2* tmp      = (int2*)mean_u;           // E*8 = 16 MB (< 25.6 MB)

    auto cdiv = [](int a, int b) { return (a + b - 1) / b; };
    const int chunk = cdiv(E, NB);
    const int NF = ND * NB;                   // 65536 flat counters

    hipMemsetAsync(hist_u, 0, (size_t)NF * 4, stream);
    hipMemsetAsync(hist_m, 0, (size_t)NF * 4, stream);
    k_hist2<<<NB, 256, 0, stream>>>(edge_src, edge_dst, hist_u, hist_m, E, chunk);

    // one-time weight fragment tables + f16 user table
    k_wprep128<<<4, 256, 0, stream>>>(c1_um_wl, c1_um_wr, wf1m);
    k_wprep128<<<4, 256, 0, stream>>>(c1_mu_wl, c1_mu_wr, wf1u);
    k_wprep128<<<4, 256, 0, stream>>>(c2_um_wl, c2_um_wr, wf2m);
    k_wprep128<<<4, 256, 0, stream>>>(c2_mu_wl, c2_mu_wr, wf2u);
    k_wprep64<<<2, 256, 0, stream>>>(dec_w1 + 64 * 64, wdm);
    k_wprep64<<<2, 256, 0, stream>>>(dec_w1, wdu);
    k_wprep256<<<8, 256, 0, stream>>>(proj_w, wpj);
    k_cvt<<<cdiv(U * 16, 256), 256, 0, stream>>>(user_emb, user16, U * 16);

    // movie-side CSR (bucket by dst>>7, width 128)
    k_scan_local<<<NF / 1024, 256, 0, stream>>>(hist_m, scanned, bsums, NF);
    k_scan_carry<<<1, 256, 0, stream>>>(bsums, NF / 1024);
    k_scan_off<<<cdiv(NF + 1, 256), 256, 0, stream>>>(scanned, bsums, off_flat, NF);
    k_scatter<<<NB, 256, 0, stream>>>(edge_dst, edge_src, off_flat, tmp, E, chunk, 7);
    k_bucket<128><<<ND, 256, 0, stream>>>(tmp, off_flat, adj_m, off_m, E, 7, M);

    // user-side CSR (bucket by src>>9, width 512)
    k_scan_local<<<NF / 1024, 256, 0, stream>>>(hist_u, scanned, bsums, NF);
    k_scan_carry<<<1, 256, 0, stream>>>(bsums, NF / 1024);
    k_scan_off<<<cdiv(NF + 1, 256), 256, 0, stream>>>(scanned, bsums, off_flat, NF);
    k_scatter<<<NB, 256, 0, stream>>>(edge_src, edge_dst, off_flat, tmp, E, chunk, 9);
    k_bucket<512><<<ND, 256, 0, stream>>>(tmp, off_flat, adj_u, off_u, E, 9, U);

    int gm = min(cdiv(M, 64), 2048);
    int gu = min(cdiv(U, 64), 2048);

    k_proj_mfma<<<gm, 256, 0, stream>>>(movie_x, wpj, proj_b, movie0, movie16, M);

    // layer 1 (gathers over f16 tables -> f16 means)
    k_agg_h<<<cdiv(M, 4), 256, 0, stream>>>(user16, adj_m, off_m, mean16_m, M);
    k_agg_h<<<cdiv(U, 4), 256, 0, stream>>>(movie16, adj_u, off_u, mean16_u, U);
    k_trans1_mfma<<<gm, 256, 0, stream>>>(mean16_m, movie16, movie0, wf1m, c1_um_bl, m_res16, M);
    k_trans1_mfma<<<gu, 256, 0, stream>>>(mean16_u, user16, user_emb, wf1u, c1_mu_bl, u_res16, U);

    // layer 2 (gathers over f16 residuals -> f16 means)
    k_agg_h<<<cdiv(M, 4), 256, 0, stream>>>(u_res16, adj_m, off_m, mean16_m, M);
    k_agg_h<<<cdiv(U, 4), 256, 0, stream>>>(m_res16, adj_u, off_u, mean16_u, U);
    // B = l2norm(m2) @ W1_bot   (into movie0 buffer)
    k_trans2_mfma<<<gm, 256, 0, stream>>>(mean16_m, m_res16, wf2m, wdm, c2_um_bl, movie0, M);
    // A = l2norm(u2) @ W1_top   (into mean_u fp32 buffer)
    k_trans2_mfma<<<gu, 256, 0, stream>>>(mean16_u, u_res16, wf2u, wdu, c2_mu_bl, mean_u, U);

    // decoder
    k_dec<<<cdiv(EL, 16), 256, 0, stream>>>(mean_u, movie0, lbl_src, lbl_dst,
                                            dec_b1, dec_w2, dec_b2, out, EL);
}